// Round 10
// baseline (4351.513 us; speedup 1.0000x reference)
//
#include <hip/hip_runtime.h>
#include <math.h>

#define Bsz 32
#define Hd  512
#define SEQ 128
#define G4H 2048
#define BH  16384   // Bsz*Hd

typedef __attribute__((ext_vector_type(8))) short bf16x8;
typedef __attribute__((ext_vector_type(4))) float f32x4;
typedef __attribute__((ext_vector_type(4))) unsigned short us4;

__device__ __forceinline__ void gload16(const void* g, void* l) {
  __builtin_amdgcn_global_load_lds(
      (const __attribute__((address_space(1))) unsigned int*)g,
      (__attribute__((address_space(3))) unsigned int*)l, 16, 0, 0);
}

// ---------------- weight pre-pack: [kk(8)][ks(64)][jj(8)], k = ks*8+kk ----------------
// jj = gate*2 + cell: j = (jj>>1)*512 + blk*2 + (jj&1)
__global__ __launch_bounds__(256) void pack_w_k(const float* __restrict__ W,
                                                float* __restrict__ out) {
  __shared__ float Wl[8][512];
  const int blk = blockIdx.x, tid = threadIdx.x;
  #pragma unroll
  for (int r = 0; r < 8; ++r) {
    int j = ((r >> 1) << 9) + (blk << 1) + (r & 1);
    Wl[r][tid] = W[j * Hd + tid];
    Wl[r][tid + 256] = W[j * Hd + tid + 256];
  }
  __syncthreads();
  #pragma unroll
  for (int q = 0; q < 16; ++q) {
    int i = tid * 16 + q;
    int kk = i >> 9, ks = (i >> 3) & 63, jj = i & 7;
    out[((size_t)blk << 12) + i] = Wl[jj][ks * 8 + kk];
  }
}

__global__ __launch_bounds__(256) void bias_sum_k(const float* __restrict__ a,
                                                  const float* __restrict__ b,
                                                  float* __restrict__ out) {
  int i = blockIdx.x * 256 + threadIdx.x;
  if (i < G4H) out[i] = a[i] + b[i];
}

__global__ __launch_bounds__(256) void embed_k(const int* __restrict__ idx,
                                               const float* __restrict__ emb,
                                               float* __restrict__ out) {
  int t = blockIdx.x * 256 + threadIdx.x;
  int m = t >> 6, e4 = (t & 63) << 2;
  *(float4*)&out[(size_t)m * 256 + e4] =
      *(const float4*)&emb[(size_t)idx[m] * 256 + e4];
}

// ---------------- fp32 -> bf16 hi/lo split ----------------
__global__ __launch_bounds__(256) void split_k(const float* __restrict__ X,
                                               unsigned short* __restrict__ hi,
                                               unsigned short* __restrict__ lo) {
  int i = (blockIdx.x * 256 + threadIdx.x) << 2;
  float4 x = *(const float4*)&X[i];
  const float* xp = (const float*)&x;
  us4 h, l;
  #pragma unroll
  for (int e = 0; e < 4; ++e) {
    float v = xp[e];
    unsigned int u = __float_as_uint(v);
    unsigned int hr = (u + 0x7fffu + ((u >> 16) & 1u)) & 0xffff0000u;
    h[e] = (unsigned short)(hr >> 16);
    float rem = v - __uint_as_float(hr);
    unsigned int u2 = __float_as_uint(rem);
    l[e] = (unsigned short)((u2 + 0x7fffu + ((u2 >> 16) & 1u)) >> 16);
  }
  *(us4*)&hi[i] = h;
  *(us4*)&lo[i] = l;
}

// ---------------- fp32 NT GEMM (input gates + fallback) ----------------
__global__ __launch_bounds__(256, 2)
void gemm_nt_k(const float* __restrict__ A, const float* __restrict__ Wt,
               const float* __restrict__ bias, float* __restrict__ C,
               int K, int ldc)
{
  __shared__ float As[32 * 68];
  __shared__ float Ws[32 * 68];
  const int tid = threadIdx.x;
  const int m0 = blockIdx.y << 6, n0 = blockIdx.x << 6;
  const int tn = tid & 15, tm = tid >> 4;
  const int lr = tid >> 2, lk = (tid & 3) << 3;
  float acc[4][4] = {};
  for (int kt = 0; kt < K; kt += 32) {
    #pragma unroll
    for (int i = 0; i < 2; ++i) {
      float4 a = *(const float4*)&A[(size_t)(m0 + lr) * K + kt + lk + (i << 2)];
      float4 w = *(const float4*)&Wt[(size_t)(n0 + lr) * K + kt + lk + (i << 2)];
      const float* ap = (const float*)&a;
      const float* wp = (const float*)&w;
      #pragma unroll
      for (int d = 0; d < 4; ++d) {
        As[(lk + (i << 2) + d) * 68 + lr] = ap[d];
        Ws[(lk + (i << 2) + d) * 68 + lr] = wp[d];
      }
    }
    __syncthreads();
    #pragma unroll 8
    for (int kk = 0; kk < 32; ++kk) {
      float4 av = *(const float4*)&As[kk * 68 + (tm << 2)];
      float4 wv = *(const float4*)&Ws[kk * 68 + (tn << 2)];
      const float* ap = (const float*)&av;
      const float* wp = (const float*)&wv;
      #pragma unroll
      for (int i = 0; i < 4; ++i)
        #pragma unroll
        for (int j = 0; j < 4; ++j)
          acc[i][j] += ap[i] * wp[j];
    }
    __syncthreads();
  }
  #pragma unroll
  for (int i = 0; i < 4; ++i) {
    float4 o;
    float* op = (float*)&o;
    #pragma unroll
    for (int j = 0; j < 4; ++j) op[j] = acc[i][j] + bias[n0 + (tn << 2) + j];
    *(float4*)&C[(size_t)(m0 + (tm << 2) + i) * ldc + n0 + (tn << 2)] = o;
  }
}

// ---------------- bf16 MFMA 3-term split projection ----------------
__global__ __launch_bounds__(256)
void gemm_bf16_split_k(const unsigned short* __restrict__ Ahi,
                       const unsigned short* __restrict__ Alo,
                       const unsigned short* __restrict__ Bhi,
                       const unsigned short* __restrict__ Blo,
                       const float* __restrict__ bias,
                       float* __restrict__ C)
{
  __shared__ unsigned short As[4096];   // [128][32]
  __shared__ unsigned short Bs[4096];   // [128][32]
  const int tid = threadIdx.x;
  const int m0 = blockIdx.x << 7, n0 = blockIdx.y << 7;
  const int lane = tid & 63, wave = tid >> 6;
  const int wr = wave >> 1, wc = wave & 1;
  const int srow = wave * 32 + (lane >> 2);
  const int sk = (lane & 3) << 3;
  const int ldse = wave * 1024 + lane * 8;
  const int fr = lane & 15, fk = (lane >> 4) << 3;

  f32x4 acc[4][4];
  #pragma unroll
  for (int a = 0; a < 4; ++a)
    #pragma unroll
    for (int b = 0; b < 4; ++b) acc[a][b] = (f32x4){0.f, 0.f, 0.f, 0.f};

  #pragma unroll 1
  for (int seg = 0; seg < 3; ++seg) {
    const unsigned short* Ab = (seg == 2) ? Alo : Ahi;
    const unsigned short* Bb = (seg == 1) ? Blo : Bhi;
    #pragma unroll 1
    for (int kt = 0; kt < 512; kt += 32) {
      gload16(Ab + (size_t)(m0 + srow) * 512 + kt + sk, &As[ldse]);
      gload16(Ab + (size_t)(m0 + srow + 16) * 512 + kt + sk, &As[ldse + 512]);
      gload16(Bb + (size_t)(n0 + srow) * 512 + kt + sk, &Bs[ldse]);
      gload16(Bb + (size_t)(n0 + srow + 16) * 512 + kt + sk, &Bs[ldse + 512]);
      __syncthreads();
      bf16x8 af[4], bf[4];
      #pragma unroll
      for (int mf = 0; mf < 4; ++mf)
        af[mf] = *(const bf16x8*)&As[(wr * 64 + mf * 16 + fr) * 32 + fk];
      #pragma unroll
      for (int nf = 0; nf < 4; ++nf)
        bf[nf] = *(const bf16x8*)&Bs[(wc * 64 + nf * 16 + fr) * 32 + fk];
      #pragma unroll
      for (int mf = 0; mf < 4; ++mf)
        #pragma unroll
        for (int nf = 0; nf < 4; ++nf)
          acc[mf][nf] = __builtin_amdgcn_mfma_f32_16x16x32_bf16(af[mf], bf[nf],
                                                                acc[mf][nf], 0, 0, 0);
      __syncthreads();
    }
  }

  const int rgrp = (lane >> 4) << 2;
  #pragma unroll
  for (int nf = 0; nf < 4; ++nf) {
    int n = n0 + wc * 64 + nf * 16 + fr;
    float bn = bias[n];
    #pragma unroll
    for (int mf = 0; mf < 4; ++mf) {
      #pragma unroll
      for (int r = 0; r < 4; ++r) {
        int m = m0 + wr * 64 + mf * 16 + rgrp + r;
        C[(size_t)m * 32000 + n] = acc[mf][nf][r] + bn;
      }
    }
  }
}

// ---------------- packed-flag sync (256 flags in 16 cachelines) ----------------
__device__ __forceinline__ void pollwait(const int* arr, int target) {
  const int tid = threadIdx.x;
  if (tid < 64) {
    const int* p = &arr[tid << 2];
    for (;;) {
      int a = __hip_atomic_load(p + 0, __ATOMIC_RELAXED, __HIP_MEMORY_SCOPE_AGENT);
      int b = __hip_atomic_load(p + 1, __ATOMIC_RELAXED, __HIP_MEMORY_SCOPE_AGENT);
      int c = __hip_atomic_load(p + 2, __ATOMIC_RELAXED, __HIP_MEMORY_SCOPE_AGENT);
      int d = __hip_atomic_load(p + 3, __ATOMIC_RELAXED, __HIP_MEMORY_SCOPE_AGENT);
      if (__all(min(min(a, b), min(c, d)) >= target)) break;
      __builtin_amdgcn_s_sleep(2);
    }
  }
  __syncthreads();
}

// ---------------- persistent LSTM: 512 threads (2 waves/SIMD), shuffle k-reduce ----------------
// Same protocol as round 9: one exchange per super-step, write-once h slots,
// sc1 write-through h stores, single packed flag per block.
__global__ __launch_bounds__(512, 1)
void lstm_seq_k(const float* __restrict__ w0p,  // packed Whh0  [256][4096]
                const float* __restrict__ w1ap, // packed Wih1
                const float* __restrict__ w1bp, // packed Whh1
                const float* __restrict__ x0pre,// [B*SEQ][2048] input gates (+biases)
                const float* __restrict__ bias1,// [2048] bih1+bhh1
                float* __restrict__ h0steps, float* __restrict__ h1steps,
                const float* __restrict__ h0init, const float* __restrict__ h1init,
                const float* __restrict__ c0init, const float* __restrict__ c1init,
                float* __restrict__ c0fin, float* __restrict__ c1fin,
                float* __restrict__ dec_out,    // [B][SEQ][Hd] or nullptr
                int* __restrict__ flag)
{
  __shared__ float w0s[4096], w1as[4096], w1bs[4096];
  __shared__ float rbuf0[2048], rbuf1[2048];   // [w(8)][bg(8)][jj^bg(8)][bi(4)]
  __shared__ float gbuf[512];                  // [0:256)=L0 gates, [256:512)=L1

  const int blk = blockIdx.x, tid = threadIdx.x;
  const int bg = tid & 7, ks = tid >> 3;       // ks in [0,64): 8 k per thread
  const int wv = tid >> 6, lane = tid & 63;
  const int n0 = blk << 1;

  // stage packed weight panels (512 threads, 2 passes)
  for (int i = tid * 4; i < 4096; i += 2048) {
    *(float4*)&w0s[i]  = *(const float4*)&w0p[((size_t)blk << 12) + i];
    *(float4*)&w1as[i] = *(const float4*)&w1ap[((size_t)blk << 12) + i];
    *(float4*)&w1bs[i] = *(const float4*)&w1bp[((size_t)blk << 12) + i];
  }

  // pointwise lanes (threads 0-127): wave0 -> L0, wave1 -> L1
  const int half = wv & 1;
  const int pr = tid & 63;
  const int cc_ = pr & 1, b2_ = pr >> 1, nn_ = n0 + cc_;
  float creg = 0.f;
  if (tid < 128) creg = (half ? c1init : c0init)[b2_ * Hd + nn_];
  // final-reduce lanes: tid<256 -> L0 (needs x), tid>=256 -> L1 (needs bias)
  const int t2 = tid & 255;
  const int rcol = t2 & 7, rb = t2 >> 3, rbgr = rb >> 2, rbi = rb & 3;
  const int rj = ((rcol >> 1) << 9) + n0 + (rcol & 1);
  const float bv = bias1[rj];
  const float* xbase = x0pre + (size_t)rb * SEQ * G4H + rj;
  __syncthreads();

  #pragma unroll 1
  for (int u = 0; u <= SEQ; ++u) {
    const bool doL0 = (u < SEQ), doL1 = (u >= 1);
    const int wbase = ks << 3;

    // x prefetch before the wait (static address; hides under poll)
    float xv = (doL0 && tid < 256) ? xbase[(size_t)u * G4H] : 0.f;

    if (u > 0) pollwait(flag, u);

    // ---- h loads: per-thread 4 b x 8 k (2 float4 each) ----
    float hA[4][8];
    {
      const float* h0p = (u == 0) ? h0init : h0steps + (size_t)(u - 1) * BH;
      #pragma unroll
      for (int bi = 0; bi < 4; ++bi) {
        int b = (bg << 2) + bi;
        float4 t0 = *(const float4*)&h0p[b * Hd + (ks << 3)];
        float4 t1 = *(const float4*)&h0p[b * Hd + (ks << 3) + 4];
        hA[bi][0] = t0.x; hA[bi][1] = t0.y; hA[bi][2] = t0.z; hA[bi][3] = t0.w;
        hA[bi][4] = t1.x; hA[bi][5] = t1.y; hA[bi][6] = t1.z; hA[bi][7] = t1.w;
      }
    }
    float hB[4][8];
    if (doL1) {
      const float* h1p = (u == 1) ? h1init : h1steps + (size_t)(u - 2) * BH;
      #pragma unroll
      for (int bi = 0; bi < 4; ++bi) {
        int b = (bg << 2) + bi;
        float4 t0 = *(const float4*)&h1p[b * Hd + (ks << 3)];
        float4 t1 = *(const float4*)&h1p[b * Hd + (ks << 3) + 4];
        hB[bi][0] = t0.x; hB[bi][1] = t0.y; hB[bi][2] = t0.z; hB[bi][3] = t0.w;
        hB[bi][4] = t1.x; hB[bi][5] = t1.y; hB[bi][6] = t1.z; hB[bi][7] = t1.w;
      }
    }

    __attribute__((aligned(16))) float acc0[8][4];
    __attribute__((aligned(16))) float acc1[8][4];
    #pragma unroll
    for (int jj = 0; jj < 8; ++jj)
      #pragma unroll
      for (int bi = 0; bi < 4; ++bi) { acc0[jj][bi] = 0.f; acc1[jj][bi] = 0.f; }

    if (doL0) {
      #pragma unroll
      for (int kk = 0; kk < 8; ++kk) {           // Whh0 . hA
        float4 wlo = *(const float4*)&w0s[(kk << 9) + wbase];
        float4 whi = *(const float4*)&w0s[(kk << 9) + wbase + 4];
        const float* wl = (const float*)&wlo;
        const float* wh = (const float*)&whi;
        #pragma unroll
        for (int jj = 0; jj < 4; ++jj)
          #pragma unroll
          for (int bi = 0; bi < 4; ++bi) {
            acc0[jj][bi]     += wl[jj] * hA[bi][kk];
            acc0[4 + jj][bi] += wh[jj] * hA[bi][kk];
          }
      }
    }
    if (doL1) {
      #pragma unroll
      for (int kk = 0; kk < 8; ++kk) {           // Wih1 . hA
        float4 wlo = *(const float4*)&w1as[(kk << 9) + wbase];
        float4 whi = *(const float4*)&w1as[(kk << 9) + wbase + 4];
        const float* wl = (const float*)&wlo;
        const float* wh = (const float*)&whi;
        #pragma unroll
        for (int jj = 0; jj < 4; ++jj)
          #pragma unroll
          for (int bi = 0; bi < 4; ++bi) {
            acc1[jj][bi]     += wl[jj] * hA[bi][kk];
            acc1[4 + jj][bi] += wh[jj] * hA[bi][kk];
          }
      }
      #pragma unroll
      for (int kk = 0; kk < 8; ++kk) {           // Whh1 . hB
        float4 wlo = *(const float4*)&w1bs[(kk << 9) + wbase];
        float4 whi = *(const float4*)&w1bs[(kk << 9) + wbase + 4];
        const float* wl = (const float*)&wlo;
        const float* wh = (const float*)&whi;
        #pragma unroll
        for (int jj = 0; jj < 4; ++jj)
          #pragma unroll
          for (int bi = 0; bi < 4; ++bi) {
            acc1[jj][bi]     += wl[jj] * hB[bi][kk];
            acc1[4 + jj][bi] += wh[jj] * hB[bi][kk];
          }
      }
    }

    // ---- in-wave k-pre-reduce (8 ks-slots per wave; xor 8/16/32 keeps bg) ----
    #pragma unroll
    for (int jj = 0; jj < 8; ++jj)
      #pragma unroll
      for (int bi = 0; bi < 4; ++bi) {
        float v0 = acc0[jj][bi];
        v0 += __shfl_xor(v0, 8, 64);
        v0 += __shfl_xor(v0, 16, 64);
        v0 += __shfl_xor(v0, 32, 64);
        acc0[jj][bi] = v0;
        float v1 = acc1[jj][bi];
        v1 += __shfl_xor(v1, 8, 64);
        v1 += __shfl_xor(v1, 16, 64);
        v1 += __shfl_xor(v1, 32, 64);
        acc1[jj][bi] = v1;
      }

    // lanes 0-7 of each wave hold bg=lane's wave-sums; write to small rbufs
    if (lane < 8) {
      #pragma unroll
      for (int jj = 0; jj < 8; ++jj) {
        *(float4*)&rbuf0[(wv << 8) + (bg << 5) + ((jj ^ bg) << 2)] = *(const float4*)acc0[jj];
        *(float4*)&rbuf1[(wv << 8) + (bg << 5) + ((jj ^ bg) << 2)] = *(const float4*)acc1[jj];
      }
    }
    __syncthreads();

    // ---- final reduce over 8 waves: L0 by tid<256, L1 by tid>=256 (parallel) ----
    if (tid < 256) {
      if (doL0) {
        float s = xv;
        #pragma unroll
        for (int w = 0; w < 8; ++w)
          s += rbuf0[(w << 8) + (rbgr << 5) + ((rcol ^ rbgr) << 2) + rbi];
        gbuf[(rcol << 5) + rb] = s;
      }
    } else {
      if (doL1) {
        float s = bv;
        #pragma unroll
        for (int w = 0; w < 8; ++w)
          s += rbuf1[(w << 8) + (rbgr << 5) + ((rcol ^ rbgr) << 2) + rbi];
        gbuf[256 + (rcol << 5) + rb] = s;
      }
    }
    __syncthreads();

    // ---- pointwise: wave0 -> L0, wave1 -> L1 ----
    if (tid < 64 && doL0) {
      float gi = gbuf[((0 + cc_) << 5) + b2_];
      float gf = gbuf[((2 + cc_) << 5) + b2_];
      float gg = gbuf[((4 + cc_) << 5) + b2_];
      float go = gbuf[((6 + cc_) << 5) + b2_];
      float i_ = 1.f / (1.f + expf(-gi));
      float f_ = 1.f / (1.f + expf(-gf));
      float o_ = 1.f / (1.f + expf(-go));
      float g_ = tanhf(gg);
      float cn = f_ * creg + i_ * g_;
      float hn = o_ * tanhf(cn);
      creg = cn;
      __hip_atomic_store(&h0steps[(size_t)u * BH + b2_ * Hd + nn_], hn,
                         __ATOMIC_RELAXED, __HIP_MEMORY_SCOPE_AGENT);
    } else if (tid >= 64 && tid < 128 && doL1) {
      const int t = u - 1;
      float gi = gbuf[256 + ((0 + cc_) << 5) + b2_];
      float gf = gbuf[256 + ((2 + cc_) << 5) + b2_];
      float gg = gbuf[256 + ((4 + cc_) << 5) + b2_];
      float go = gbuf[256 + ((6 + cc_) << 5) + b2_];
      float i_ = 1.f / (1.f + expf(-gi));
      float f_ = 1.f / (1.f + expf(-gf));
      float o_ = 1.f / (1.f + expf(-go));
      float g_ = tanhf(gg);
      float cn = f_ * creg + i_ * g_;
      float hn = o_ * tanhf(cn);
      creg = cn;
      __hip_atomic_store(&h1steps[(size_t)t * BH + b2_ * Hd + nn_], hn,
                         __ATOMIC_RELAXED, __HIP_MEMORY_SCOPE_AGENT);
      if (dec_out) dec_out[((size_t)b2_ * SEQ + t) * Hd + nn_] = hn;
    }

    // drain write-through stores across all waves, then single publish
    asm volatile("s_waitcnt vmcnt(0)" ::: "memory");
    __syncthreads();
    if (tid == 0)
      __hip_atomic_store(&flag[blk], u + 1,
                         __ATOMIC_RELAXED, __HIP_MEMORY_SCOPE_AGENT);
  }

  // final c handoff
  if (tid < 128) {
    float* cf = half ? c1fin : c0fin;
    cf[b2_ * Hd + nn_] = creg;
  }
}

// ---------------- host ----------------
extern "C" void kernel_launch(void* const* d_in, const int* in_sizes, int n_in,
                              void* d_out, int out_size, void* d_ws, size_t ws_size,
                              hipStream_t stream) {
  const int*   src  = (const int*)d_in[0];
  const int*   tgt  = (const int*)d_in[1];
  const float* emb  = (const float*)d_in[2];
  const float* Wout = (const float*)d_in[3];
  const float* bout = (const float*)d_in[4];
  const float* eWih0 = (const float*)d_in[5];
  const float* eWhh0 = (const float*)d_in[6];
  const float* ebih0 = (const float*)d_in[7];
  const float* ebhh0 = (const float*)d_in[8];
  const float* eWih1 = (const float*)d_in[9];
  const float* eWhh1 = (const float*)d_in[10];
  const float* ebih1 = (const float*)d_in[11];
  const float* ebhh1 = (const float*)d_in[12];
  const float* dWih0 = (const float*)d_in[13];
  const float* dWhh0 = (const float*)d_in[14];
  const float* dbih0 = (const float*)d_in[15];
  const float* dbhh0 = (const float*)d_in[16];
  const float* dWih1 = (const float*)d_in[17];
  const float* dWhh1 = (const float*)d_in[18];
  const float* dbih1 = (const float*)d_in[19];
  const float* dbhh1 = (const float*)d_in[20];

  float* ws = (float*)d_ws;
  char*  wsb = (char*)d_ws;
  // float offsets
  const size_t OFF_EMB  = 0;          // dead after input gemms
  const size_t OFF_X0   = 1048576;
  const size_t OFF_W0E  = 9437184;
  const size_t OFF_W1AE = 10485760;
  const size_t OFF_W1BE = 11534336;
  const size_t OFF_W0D  = 12582912;
  const size_t OFF_W1AD = 13631488;
  const size_t OFF_W1BD = 14680064;
  const size_t OFF_BS0E = 15728640;
  const size_t OFF_B1E  = 15730688;
  const size_t OFF_BS0D = 15732736;
  const size_t OFF_B1D  = 15734784;
  const size_t OFF_H0   = 15736832;   // 128*BH (per-step h0 slots)
  const size_t OFF_H1   = 17833984;   // 128*BH
  const size_t OFF_C0   = 19931136;   // BH (enc-final c0 -> dec init)
  const size_t OFF_C1   = 19947520;   // BH
  const size_t OFF_Z    = 19963904;   // BH zeros
  const size_t OFF_BAR  = 19980288;   // packed flags: enc at +0, dec at +256
  const size_t OFF_DOUT = 20013056;   // 2,097,152 f -> byte end 88,440,832
  unsigned short* Ahi = (unsigned short*)(wsb + 88440832);   // 4096*512
  unsigned short* Alo = (unsigned short*)(wsb + 92635136);   // 4096*512
  unsigned short* Bhi = (unsigned short*)(wsb + 0);          // 32000*512 (dead low region)
  unsigned short* Blo = (unsigned short*)(wsb + 32768000);
  const bool use_mfma = ws_size >= 96829440ull;

  int* eflag = (int*)(ws + OFF_BAR);
  int* dflag = eflag + 256;

  // pack weights + bias sums
  pack_w_k<<<256, 256, 0, stream>>>(eWhh0, ws + OFF_W0E);
  pack_w_k<<<256, 256, 0, stream>>>(eWih1, ws + OFF_W1AE);
  pack_w_k<<<256, 256, 0, stream>>>(eWhh1, ws + OFF_W1BE);
  pack_w_k<<<256, 256, 0, stream>>>(dWhh0, ws + OFF_W0D);
  pack_w_k<<<256, 256, 0, stream>>>(dWih1, ws + OFF_W1AD);
  pack_w_k<<<256, 256, 0, stream>>>(dWhh1, ws + OFF_W1BD);
  bias_sum_k<<<8, 256, 0, stream>>>(ebih0, ebhh0, ws + OFF_BS0E);
  bias_sum_k<<<8, 256, 0, stream>>>(ebih1, ebhh1, ws + OFF_B1E);
  bias_sum_k<<<8, 256, 0, stream>>>(dbih0, dbhh0, ws + OFF_BS0D);
  bias_sum_k<<<8, 256, 0, stream>>>(dbih1, dbhh1, ws + OFF_B1D);

  // zero zbuf + flags every call (graph replay safe)
  hipMemsetAsync(ws + OFF_Z, 0, (size_t)(BH + 16384) * 4, stream);

  // encoder
  embed_k<<<1024, 256, 0, stream>>>(src, emb, ws + OFF_EMB);
  gemm_nt_k<<<dim3(32, 64), 256, 0, stream>>>(ws + OFF_EMB, eWih0, ws + OFF_BS0E,
                                              ws + OFF_X0, 256, 2048);
  lstm_seq_k<<<256, 512, 0, stream>>>(ws + OFF_W0E, ws + OFF_W1AE, ws + OFF_W1BE,
                                      ws + OFF_X0, ws + OFF_B1E,
                                      ws + OFF_H0, ws + OFF_H1,
                                      ws + OFF_Z, ws + OFF_Z,      // h inits (zeros)
                                      ws + OFF_Z, ws + OFF_Z,      // c inits (zeros)
                                      ws + OFF_C0, ws + OFF_C1,    // c finals
                                      nullptr, eflag);

  // decoder (inits = encoder finals)
  embed_k<<<1024, 256, 0, stream>>>(tgt, emb, ws + OFF_EMB);
  gemm_nt_k<<<dim3(32, 64), 256, 0, stream>>>(ws + OFF_EMB, dWih0, ws + OFF_BS0D,
                                              ws + OFF_X0, 256, 2048);
  lstm_seq_k<<<256, 512, 0, stream>>>(ws + OFF_W0D, ws + OFF_W1AD, ws + OFF_W1BD,
                                      ws + OFF_X0, ws + OFF_B1D,
                                      ws + OFF_H0, ws + OFF_H1,
                                      ws + OFF_H0 + (size_t)127 * BH,
                                      ws + OFF_H1 + (size_t)127 * BH,
                                      ws + OFF_C0, ws + OFF_C1,
                                      ws + OFF_C0, ws + OFF_C1,
                                      ws + OFF_DOUT, dflag);

  // vocab projection
  if (use_mfma) {
    split_k<<<2048, 256, 0, stream>>>(ws + OFF_DOUT, Ahi, Alo);
    split_k<<<16000, 256, 0, stream>>>(Wout, Bhi, Blo);   // overlays dead low region
    gemm_bf16_split_k<<<dim3(32, 250), 256, 0, stream>>>(Ahi, Alo, Bhi, Blo,
                                                         bout, (float*)d_out);
  } else {
    gemm_nt_k<<<dim3(500, 64), 256, 0, stream>>>(ws + OFF_DOUT, Wout, bout,
                                                 (float*)d_out, 512, 32000);
  }
}

// Round 11
// 3764.144 us; speedup vs baseline: 1.1560x; 1.1560x over previous
//
#include <hip/hip_runtime.h>
#include <math.h>

#define Bsz 32
#define Hd  512
#define SEQ 128
#define G4H 2048
#define BH  16384   // Bsz*Hd

typedef __attribute__((ext_vector_type(8))) short bf16x8;
typedef __attribute__((ext_vector_type(4))) float f32x4;
typedef __attribute__((ext_vector_type(4))) unsigned short us4;

__device__ __forceinline__ void gload16(const void* g, void* l) {
  __builtin_amdgcn_global_load_lds(
      (const __attribute__((address_space(1))) unsigned int*)g,
      (__attribute__((address_space(3))) unsigned int*)l, 16, 0, 0);
}

// ---------------- weight pre-pack (R9 layout: [kk16][ks2 8][jj8]) ----------------
__global__ __launch_bounds__(256) void pack_w_k(const float* __restrict__ W,
                                                float* __restrict__ out) {
  __shared__ float Wl[8][512];
  const int blk = blockIdx.x, tid = threadIdx.x;
  #pragma unroll
  for (int r = 0; r < 8; ++r) {
    int j = ((r >> 1) << 9) + (blk << 1) + (r & 1);
    Wl[r][tid] = W[j * Hd + tid];
    Wl[r][tid + 256] = W[j * Hd + tid + 256];
  }
  __syncthreads();
  #pragma unroll
  for (int q = 0; q < 16; ++q) {
    int i = tid * 16 + q;
    int kk = i >> 8, rest = i & 255, ks2 = rest >> 3, jj = rest & 7;
    out[((size_t)blk << 12) + i] = Wl[jj][(ks2 << 4) + kk];
  }
}

__global__ __launch_bounds__(256) void bias_sum_k(const float* __restrict__ a,
                                                  const float* __restrict__ b,
                                                  float* __restrict__ out) {
  int i = blockIdx.x * 256 + threadIdx.x;
  if (i < G4H) out[i] = a[i] + b[i];
}

__global__ __launch_bounds__(256) void embed_k(const int* __restrict__ idx,
                                               const float* __restrict__ emb,
                                               float* __restrict__ out) {
  int t = blockIdx.x * 256 + threadIdx.x;
  int m = t >> 6, e4 = (t & 63) << 2;
  *(float4*)&out[(size_t)m * 256 + e4] =
      *(const float4*)&emb[(size_t)idx[m] * 256 + e4];
}

// ---------------- fp32 -> bf16 hi/lo split ----------------
__global__ __launch_bounds__(256) void split_k(const float* __restrict__ X,
                                               unsigned short* __restrict__ hi,
                                               unsigned short* __restrict__ lo) {
  int i = (blockIdx.x * 256 + threadIdx.x) << 2;
  float4 x = *(const float4*)&X[i];
  const float* xp = (const float*)&x;
  us4 h, l;
  #pragma unroll
  for (int e = 0; e < 4; ++e) {
    float v = xp[e];
    unsigned int u = __float_as_uint(v);
    unsigned int hr = (u + 0x7fffu + ((u >> 16) & 1u)) & 0xffff0000u;
    h[e] = (unsigned short)(hr >> 16);
    float rem = v - __uint_as_float(hr);
    unsigned int u2 = __float_as_uint(rem);
    l[e] = (unsigned short)((u2 + 0x7fffu + ((u2 >> 16) & 1u)) >> 16);
  }
  *(us4*)&hi[i] = h;
  *(us4*)&lo[i] = l;
}

// ---------------- fp32 NT GEMM (fallback only) ----------------
__global__ __launch_bounds__(256, 2)
void gemm_nt_k(const float* __restrict__ A, const float* __restrict__ Wt,
               const float* __restrict__ bias, float* __restrict__ C,
               int K, int ldc)
{
  __shared__ float As[32 * 68];
  __shared__ float Ws[32 * 68];
  const int tid = threadIdx.x;
  const int m0 = blockIdx.y << 6, n0 = blockIdx.x << 6;
  const int tn = tid & 15, tm = tid >> 4;
  const int lr = tid >> 2, lk = (tid & 3) << 3;
  float acc[4][4] = {};
  for (int kt = 0; kt < K; kt += 32) {
    #pragma unroll
    for (int i = 0; i < 2; ++i) {
      float4 a = *(const float4*)&A[(size_t)(m0 + lr) * K + kt + lk + (i << 2)];
      float4 w = *(const float4*)&Wt[(size_t)(n0 + lr) * K + kt + lk + (i << 2)];
      const float* ap = (const float*)&a;
      const float* wp = (const float*)&w;
      #pragma unroll
      for (int d = 0; d < 4; ++d) {
        As[(lk + (i << 2) + d) * 68 + lr] = ap[d];
        Ws[(lk + (i << 2) + d) * 68 + lr] = wp[d];
      }
    }
    __syncthreads();
    #pragma unroll 8
    for (int kk = 0; kk < 32; ++kk) {
      float4 av = *(const float4*)&As[kk * 68 + (tm << 2)];
      float4 wv = *(const float4*)&Ws[kk * 68 + (tn << 2)];
      const float* ap = (const float*)&av;
      const float* wp = (const float*)&wv;
      #pragma unroll
      for (int i = 0; i < 4; ++i)
        #pragma unroll
        for (int j = 0; j < 4; ++j)
          acc[i][j] += ap[i] * wp[j];
    }
    __syncthreads();
  }
  #pragma unroll
  for (int i = 0; i < 4; ++i) {
    float4 o;
    float* op = (float*)&o;
    #pragma unroll
    for (int j = 0; j < 4; ++j) op[j] = acc[i][j] + bias[n0 + (tn << 2) + j];
    *(float4*)&C[(size_t)(m0 + (tm << 2) + i) * ldc + n0 + (tn << 2)] = o;
  }
}

// ---------------- bf16 MFMA 3-term split GEMM (K, ldc parameterized) ----------------
// C[m][n] = sum_k A[m][k]*B[n][k] + bias[n]; 128x128 tile, 4 waves 64x64 each.
__global__ __launch_bounds__(256)
void gemm_bfs_k(const unsigned short* __restrict__ Ahi,
                const unsigned short* __restrict__ Alo,
                const unsigned short* __restrict__ Bhi,
                const unsigned short* __restrict__ Blo,
                const float* __restrict__ bias,
                float* __restrict__ C, int K, int ldc)
{
  __shared__ unsigned short As[4096];   // [128][32]
  __shared__ unsigned short Bs[4096];   // [128][32]
  const int tid = threadIdx.x;
  const int m0 = blockIdx.x << 7, n0 = blockIdx.y << 7;
  const int lane = tid & 63, wave = tid >> 6;
  const int wr = wave >> 1, wc = wave & 1;
  const int srow = wave * 32 + (lane >> 2);
  const int sk = (lane & 3) << 3;
  const int ldse = wave * 1024 + lane * 8;
  const int fr = lane & 15, fk = (lane >> 4) << 3;

  f32x4 acc[4][4];
  #pragma unroll
  for (int a = 0; a < 4; ++a)
    #pragma unroll
    for (int b = 0; b < 4; ++b) acc[a][b] = (f32x4){0.f, 0.f, 0.f, 0.f};

  #pragma unroll 1
  for (int seg = 0; seg < 3; ++seg) {
    const unsigned short* Ab = (seg == 2) ? Alo : Ahi;
    const unsigned short* Bb = (seg == 1) ? Blo : Bhi;
    #pragma unroll 1
    for (int kt = 0; kt < K; kt += 32) {
      gload16(Ab + (size_t)(m0 + srow) * K + kt + sk, &As[ldse]);
      gload16(Ab + (size_t)(m0 + srow + 16) * K + kt + sk, &As[ldse + 512]);
      gload16(Bb + (size_t)(n0 + srow) * K + kt + sk, &Bs[ldse]);
      gload16(Bb + (size_t)(n0 + srow + 16) * K + kt + sk, &Bs[ldse + 512]);
      __syncthreads();
      bf16x8 af[4], bf[4];
      #pragma unroll
      for (int mf = 0; mf < 4; ++mf)
        af[mf] = *(const bf16x8*)&As[(wr * 64 + mf * 16 + fr) * 32 + fk];
      #pragma unroll
      for (int nf = 0; nf < 4; ++nf)
        bf[nf] = *(const bf16x8*)&Bs[(wc * 64 + nf * 16 + fr) * 32 + fk];
      #pragma unroll
      for (int mf = 0; mf < 4; ++mf)
        #pragma unroll
        for (int nf = 0; nf < 4; ++nf)
          acc[mf][nf] = __builtin_amdgcn_mfma_f32_16x16x32_bf16(af[mf], bf[nf],
                                                                acc[mf][nf], 0, 0, 0);
      __syncthreads();
    }
  }

  const int rgrp = (lane >> 4) << 2;
  #pragma unroll
  for (int nf = 0; nf < 4; ++nf) {
    int n = n0 + wc * 64 + nf * 16 + fr;
    float bn = bias[n];
    #pragma unroll
    for (int mf = 0; mf < 4; ++mf) {
      #pragma unroll
      for (int r = 0; r < 4; ++r) {
        int m = m0 + wr * 64 + mf * 16 + rgrp + r;
        C[(size_t)m * ldc + n] = acc[mf][nf][r] + bn;
      }
    }
  }
}

// ---------------- packed-flag sync (256 flags in 16 cachelines) ----------------
__device__ __forceinline__ void pollwait(const int* arr, int target) {
  const int tid = threadIdx.x;
  if (tid < 64) {
    const int* p = &arr[tid << 2];
    for (;;) {
      int a = __hip_atomic_load(p + 0, __ATOMIC_RELAXED, __HIP_MEMORY_SCOPE_AGENT);
      int b = __hip_atomic_load(p + 1, __ATOMIC_RELAXED, __HIP_MEMORY_SCOPE_AGENT);
      int c = __hip_atomic_load(p + 2, __ATOMIC_RELAXED, __HIP_MEMORY_SCOPE_AGENT);
      int d = __hip_atomic_load(p + 3, __ATOMIC_RELAXED, __HIP_MEMORY_SCOPE_AGENT);
      if (__all(min(min(a, b), min(c, d)) >= target)) break;
      __builtin_amdgcn_s_sleep(8);
    }
  }
  __syncthreads();
}

// ---------------- persistent LSTM: R9 structure, packed flags ----------------
// Super-step u: L0(t=u) + L1(t=u-1); one pollwait(flag,u), one publish(flag=u+1).
__global__ __launch_bounds__(256, 1)
void lstm_seq_k(const float* __restrict__ w0p,  // packed Whh0  [256][4096]
                const float* __restrict__ w1ap, // packed Wih1
                const float* __restrict__ w1bp, // packed Whh1
                const float* __restrict__ x0pre,// [B*SEQ][2048] input gates (+biases)
                const float* __restrict__ bias1,// [2048] bih1+bhh1
                float* __restrict__ h0steps, float* __restrict__ h1steps,
                const float* __restrict__ h0init, const float* __restrict__ h1init,
                const float* __restrict__ c0init, const float* __restrict__ c1init,
                float* __restrict__ c0fin, float* __restrict__ c1fin,
                float* __restrict__ dec_out,    // [B][SEQ][Hd] or nullptr
                int* __restrict__ flag)
{
  __shared__ float w0s[4096], w1as[4096], w1bs[4096];
  __shared__ float rbuf[16384];   // [0:8192)=L0, [8192:16384)=L1
  __shared__ float gbuf[512];     // [0:256)=L0 gates, [256:512)=L1

  const int blk = blockIdx.x, tid = threadIdx.x;
  const int bg = tid & 7, ks = tid >> 3;
  const int n0 = blk << 1;

  // stage all three packed weight panels once
  for (int i = tid * 4; i < 4096; i += 1024) {
    *(float4*)&w0s[i]  = *(const float4*)&w0p[((size_t)blk << 12) + i];
    *(float4*)&w1as[i] = *(const float4*)&w1ap[((size_t)blk << 12) + i];
    *(float4*)&w1bs[i] = *(const float4*)&w1bp[((size_t)blk << 12) + i];
  }

  // loop-invariant per-thread state
  const int half = (tid >> 6) & 1;               // wave0 -> L0 pointwise, wave1 -> L1
  const int pr = tid & 63;
  const int cc_ = pr & 1, b2_ = pr >> 1, nn_ = n0 + cc_;
  float creg = 0.f;
  if (tid < 128) creg = (half ? c1init : c0init)[b2_ * Hd + nn_];
  const int rcol = tid & 7, rb = tid >> 3, rbgr = rb >> 2, rbi = rb & 3;
  const int rj = ((rcol >> 1) << 9) + n0 + (rcol & 1);
  const float bv = bias1[rj];
  const float* xbase = x0pre + (size_t)rb * SEQ * G4H + rj;
  __syncthreads();

  #pragma unroll 1
  for (int u = 0; u <= SEQ; ++u) {
    const bool doL0 = (u < SEQ), doL1 = (u >= 1);
    const int wbase = ks << 3;

    // x prefetch before the wait (static address; latency hides under poll)
    float xv = doL0 ? xbase[(size_t)u * G4H] : 0.f;

    if (u > 0) pollwait(flag, u);   // all of super-step u-1's outputs visible

    // ---- h loads (coalesced float4, fresh per-step addresses) ----
    float hA[4][16];
    {
      const float* h0p = (u == 0) ? h0init : h0steps + (size_t)(u - 1) * BH;
      #pragma unroll
      for (int bi = 0; bi < 4; ++bi) {
        int b = (bg << 2) + bi;
        #pragma unroll
        for (int q = 0; q < 4; ++q) {
          float4 t = *(const float4*)&h0p[b * Hd + (ks << 4) + (q << 2)];
          hA[bi][q * 4 + 0] = t.x; hA[bi][q * 4 + 1] = t.y;
          hA[bi][q * 4 + 2] = t.z; hA[bi][q * 4 + 3] = t.w;
        }
      }
    }
    float hB[4][16];
    if (doL1) {
      const float* h1p = (u == 1) ? h1init : h1steps + (size_t)(u - 2) * BH;
      #pragma unroll
      for (int bi = 0; bi < 4; ++bi) {
        int b = (bg << 2) + bi;
        #pragma unroll
        for (int q = 0; q < 4; ++q) {
          float4 t = *(const float4*)&h1p[b * Hd + (ks << 4) + (q << 2)];
          hB[bi][q * 4 + 0] = t.x; hB[bi][q * 4 + 1] = t.y;
          hB[bi][q * 4 + 2] = t.z; hB[bi][q * 4 + 3] = t.w;
        }
      }
    }

    __attribute__((aligned(16))) float acc0[8][4];
    __attribute__((aligned(16))) float acc1[8][4];
    #pragma unroll
    for (int jj = 0; jj < 8; ++jj)
      #pragma unroll
      for (int bi = 0; bi < 4; ++bi) { acc0[jj][bi] = 0.f; acc1[jj][bi] = 0.f; }

    if (doL0) {
      #pragma unroll
      for (int kk = 0; kk < 16; ++kk) {          // Whh0 . hA
        float4 wlo = *(const float4*)&w0s[(kk << 8) + wbase];
        float4 whi = *(const float4*)&w0s[(kk << 8) + wbase + 4];
        const float* wl = (const float*)&wlo;
        const float* wh = (const float*)&whi;
        #pragma unroll
        for (int jj = 0; jj < 4; ++jj)
          #pragma unroll
          for (int bi = 0; bi < 4; ++bi) {
            acc0[jj][bi]     += wl[jj] * hA[bi][kk];
            acc0[4 + jj][bi] += wh[jj] * hA[bi][kk];
          }
      }
    }
    if (doL1) {
      #pragma unroll
      for (int kk = 0; kk < 16; ++kk) {          // Wih1 . hA
        float4 wlo = *(const float4*)&w1as[(kk << 8) + wbase];
        float4 whi = *(const float4*)&w1as[(kk << 8) + wbase + 4];
        const float* wl = (const float*)&wlo;
        const float* wh = (const float*)&whi;
        #pragma unroll
        for (int jj = 0; jj < 4; ++jj)
          #pragma unroll
          for (int bi = 0; bi < 4; ++bi) {
            acc1[jj][bi]     += wl[jj] * hA[bi][kk];
            acc1[4 + jj][bi] += wh[jj] * hA[bi][kk];
          }
      }
      #pragma unroll
      for (int kk = 0; kk < 16; ++kk) {          // Whh1 . hB
        float4 wlo = *(const float4*)&w1bs[(kk << 8) + wbase];
        float4 whi = *(const float4*)&w1bs[(kk << 8) + wbase + 4];
        const float* wl = (const float*)&wlo;
        const float* wh = (const float*)&whi;
        #pragma unroll
        for (int jj = 0; jj < 4; ++jj)
          #pragma unroll
          for (int bi = 0; bi < 4; ++bi) {
            acc1[jj][bi]     += wl[jj] * hB[bi][kk];
            acc1[4 + jj][bi] += wh[jj] * hB[bi][kk];
          }
      }
    }

    // ---- both reductions through doubled rbuf, one barrier pair ----
    if (doL0) {
      #pragma unroll
      for (int jj = 0; jj < 8; ++jj)
        *(float4*)&rbuf[(ks << 8) + (bg << 5) + ((jj ^ bg) << 2)] = *(const float4*)acc0[jj];
    }
    if (doL1) {
      #pragma unroll
      for (int jj = 0; jj < 8; ++jj)
        *(float4*)&rbuf[8192 + (ks << 8) + (bg << 5) + ((jj ^ bg) << 2)] = *(const float4*)acc1[jj];
    }
    __syncthreads();
    if (doL0) {
      float s = xv;
      #pragma unroll 8
      for (int k2 = 0; k2 < 32; ++k2)
        s += rbuf[(k2 << 8) + (rbgr << 5) + ((rcol ^ rbgr) << 2) + rbi];
      gbuf[(rcol << 5) + rb] = s;
    }
    if (doL1) {
      float s = bv;
      #pragma unroll 8
      for (int k2 = 0; k2 < 32; ++k2)
        s += rbuf[8192 + (k2 << 8) + (rbgr << 5) + ((rcol ^ rbgr) << 2) + rbi];
      gbuf[256 + (rcol << 5) + rb] = s;
    }
    __syncthreads();

    // ---- pointwise: wave0 -> L0, wave1 -> L1 (parallel, coalesced stores) ----
    if (tid < 64 && doL0) {
      float gi = gbuf[((0 + cc_) << 5) + b2_];
      float gf = gbuf[((2 + cc_) << 5) + b2_];
      float gg = gbuf[((4 + cc_) << 5) + b2_];
      float go = gbuf[((6 + cc_) << 5) + b2_];
      float i_ = 1.f / (1.f + expf(-gi));
      float f_ = 1.f / (1.f + expf(-gf));
      float o_ = 1.f / (1.f + expf(-go));
      float g_ = tanhf(gg);
      float cn = f_ * creg + i_ * g_;
      float hn = o_ * tanhf(cn);
      creg = cn;
      __hip_atomic_store(&h0steps[(size_t)u * BH + b2_ * Hd + nn_], hn,
                         __ATOMIC_RELAXED, __HIP_MEMORY_SCOPE_AGENT);
    } else if (tid >= 64 && tid < 128 && doL1) {
      const int t = u - 1;
      float gi = gbuf[256 + ((0 + cc_) << 5) + b2_];
      float gf = gbuf[256 + ((2 + cc_) << 5) + b2_];
      float gg = gbuf[256 + ((4 + cc_) << 5) + b2_];
      float go = gbuf[256 + ((6 + cc_) << 5) + b2_];
      float i_ = 1.f / (1.f + expf(-gi));
      float f_ = 1.f / (1.f + expf(-gf));
      float o_ = 1.f / (1.f + expf(-go));
      float g_ = tanhf(gg);
      float cn = f_ * creg + i_ * g_;
      float hn = o_ * tanhf(cn);
      creg = cn;
      __hip_atomic_store(&h1steps[(size_t)t * BH + b2_ * Hd + nn_], hn,
                         __ATOMIC_RELAXED, __HIP_MEMORY_SCOPE_AGENT);
      if (dec_out) dec_out[((size_t)b2_ * SEQ + t) * Hd + nn_] = hn;
    }

    // drain every wave's write-through stores, then single publish
    asm volatile("s_waitcnt vmcnt(0)" ::: "memory");
    __syncthreads();
    if (tid == 0)
      __hip_atomic_store(&flag[blk], u + 1,
                         __ATOMIC_RELAXED, __HIP_MEMORY_SCOPE_AGENT);
  }

  // final c handoff
  if (tid < 128) {
    float* cf = half ? c1fin : c0fin;
    cf[b2_ * Hd + nn_] = creg;
  }
}

// ---------------- host ----------------
extern "C" void kernel_launch(void* const* d_in, const int* in_sizes, int n_in,
                              void* d_out, int out_size, void* d_ws, size_t ws_size,
                              hipStream_t stream) {
  const int*   src  = (const int*)d_in[0];
  const int*   tgt  = (const int*)d_in[1];
  const float* emb  = (const float*)d_in[2];
  const float* Wout = (const float*)d_in[3];
  const float* bout = (const float*)d_in[4];
  const float* eWih0 = (const float*)d_in[5];
  const float* eWhh0 = (const float*)d_in[6];
  const float* ebih0 = (const float*)d_in[7];
  const float* ebhh0 = (const float*)d_in[8];
  const float* eWih1 = (const float*)d_in[9];
  const float* eWhh1 = (const float*)d_in[10];
  const float* ebih1 = (const float*)d_in[11];
  const float* ebhh1 = (const float*)d_in[12];
  const float* dWih0 = (const float*)d_in[13];
  const float* dWhh0 = (const float*)d_in[14];
  const float* dbih0 = (const float*)d_in[15];
  const float* dbhh0 = (const float*)d_in[16];
  const float* dWih1 = (const float*)d_in[17];
  const float* dWhh1 = (const float*)d_in[18];
  const float* dbih1 = (const float*)d_in[19];
  const float* dbhh1 = (const float*)d_in[20];

  float* ws = (float*)d_ws;
  char*  wsb = (char*)d_ws;
  // float offsets
  const size_t OFF_EMB  = 0;          // dead after input gemms
  const size_t OFF_X0   = 1048576;
  const size_t OFF_W0E  = 9437184;
  const size_t OFF_W1AE = 10485760;
  const size_t OFF_W1BE = 11534336;
  const size_t OFF_W0D  = 12582912;
  const size_t OFF_W1AD = 13631488;
  const size_t OFF_W1BD = 14680064;
  const size_t OFF_BS0E = 15728640;
  const size_t OFF_B1E  = 15730688;
  const size_t OFF_BS0D = 15732736;
  const size_t OFF_B1D  = 15734784;
  const size_t OFF_H0   = 15736832;   // 128*BH (per-step h0 slots)
  const size_t OFF_H1   = 17833984;   // 128*BH
  const size_t OFF_C0   = 19931136;   // BH (enc-final c0 -> dec init)
  const size_t OFF_C1   = 19947520;   // BH
  const size_t OFF_Z    = 19963904;   // BH zeros
  const size_t OFF_BAR  = 19980288;   // packed flags: enc at +0, dec at +256
  const size_t OFF_DOUT = 20013056;   // 2,097,152 f -> byte end 88,440,832
  // bf16 overlays
  unsigned short* Ahi = (unsigned short*)(wsb + 88440832);   // 4096*512 (projection A)
  unsigned short* Alo = (unsigned short*)(wsb + 92635136);
  unsigned short* Bhi = (unsigned short*)(wsb + 0);          // 32000*512 (dead low region)
  unsigned short* Blo = (unsigned short*)(wsb + 32768000);
  // input-gemm overlays: Ehi/Elo in DOUT region (dead until dec LSTM);
  // WIhi/WIlo in the Ahi region (dead until projection).
  unsigned short* Ehi  = (unsigned short*)(wsb + 80052224);  // = OFF_DOUT*4: 4096*256
  unsigned short* Elo  = (unsigned short*)(wsb + 82149376);  // +2MB
  unsigned short* WIhi = (unsigned short*)(wsb + 88440832);  // 2048*256 (reused enc/dec)
  unsigned short* WIlo = (unsigned short*)(wsb + 89489408);
  const bool use_mfma = ws_size >= 96829440ull;

  int* eflag = (int*)(ws + OFF_BAR);
  int* dflag = eflag + 256;

  // pack weights + bias sums
  pack_w_k<<<256, 256, 0, stream>>>(eWhh0, ws + OFF_W0E);
  pack_w_k<<<256, 256, 0, stream>>>(eWih1, ws + OFF_W1AE);
  pack_w_k<<<256, 256, 0, stream>>>(eWhh1, ws + OFF_W1BE);
  pack_w_k<<<256, 256, 0, stream>>>(dWhh0, ws + OFF_W0D);
  pack_w_k<<<256, 256, 0, stream>>>(dWih1, ws + OFF_W1AD);
  pack_w_k<<<256, 256, 0, stream>>>(dWhh1, ws + OFF_W1BD);
  bias_sum_k<<<8, 256, 0, stream>>>(ebih0, ebhh0, ws + OFF_BS0E);
  bias_sum_k<<<8, 256, 0, stream>>>(ebih1, ebhh1, ws + OFF_B1E);
  bias_sum_k<<<8, 256, 0, stream>>>(dbih0, dbhh0, ws + OFF_BS0D);
  bias_sum_k<<<8, 256, 0, stream>>>(dbih1, dbhh1, ws + OFF_B1D);

  // zero zbuf + flags every call (graph replay safe)
  hipMemsetAsync(ws + OFF_Z, 0, (size_t)(BH + 16384) * 4, stream);

  // ---- encoder ----
  embed_k<<<1024, 256, 0, stream>>>(src, emb, ws + OFF_EMB);
  if (use_mfma) {
    split_k<<<1024, 256, 0, stream>>>(ws + OFF_EMB, Ehi, Elo);
    split_k<<<512, 256, 0, stream>>>(eWih0, WIhi, WIlo);
    gemm_bfs_k<<<dim3(32, 16), 256, 0, stream>>>(Ehi, Elo, WIhi, WIlo,
                                                 ws + OFF_BS0E, ws + OFF_X0, 256, 2048);
  } else {
    gemm_nt_k<<<dim3(32, 64), 256, 0, stream>>>(ws + OFF_EMB, eWih0, ws + OFF_BS0E,
                                                ws + OFF_X0, 256, 2048);
  }
  lstm_seq_k<<<256, 256, 0, stream>>>(ws + OFF_W0E, ws + OFF_W1AE, ws + OFF_W1BE,
                                      ws + OFF_X0, ws + OFF_B1E,
                                      ws + OFF_H0, ws + OFF_H1,
                                      ws + OFF_Z, ws + OFF_Z,      // h inits (zeros)
                                      ws + OFF_Z, ws + OFF_Z,      // c inits (zeros)
                                      ws + OFF_C0, ws + OFF_C1,    // c finals
                                      nullptr, eflag);

  // ---- decoder (inits = encoder finals) ----
  embed_k<<<1024, 256, 0, stream>>>(tgt, emb, ws + OFF_EMB);
  if (use_mfma) {
    split_k<<<1024, 256, 0, stream>>>(ws + OFF_EMB, Ehi, Elo);
    split_k<<<512, 256, 0, stream>>>(dWih0, WIhi, WIlo);
    gemm_bfs_k<<<dim3(32, 16), 256, 0, stream>>>(Ehi, Elo, WIhi, WIlo,
                                                 ws + OFF_BS0D, ws + OFF_X0, 256, 2048);
  } else {
    gemm_nt_k<<<dim3(32, 64), 256, 0, stream>>>(ws + OFF_EMB, dWih0, ws + OFF_BS0D,
                                                ws + OFF_X0, 256, 2048);
  }
  lstm_seq_k<<<256, 256, 0, stream>>>(ws + OFF_W0D, ws + OFF_W1AD, ws + OFF_W1BD,
                                      ws + OFF_X0, ws + OFF_B1D,
                                      ws + OFF_H0, ws + OFF_H1,
                                      ws + OFF_H0 + (size_t)127 * BH,
                                      ws + OFF_H1 + (size_t)127 * BH,
                                      ws + OFF_C0, ws + OFF_C1,
                                      ws + OFF_C0, ws + OFF_C1,
                                      ws + OFF_DOUT, dflag);

  // ---- vocab projection ----
  if (use_mfma) {
    split_k<<<2048, 256, 0, stream>>>(ws + OFF_DOUT, Ahi, Alo);
    split_k<<<16000, 256, 0, stream>>>(Wout, Bhi, Blo);   // overlays dead low region
    gemm_bfs_k<<<dim3(32, 250), 256, 0, stream>>>(Ahi, Alo, Bhi, Blo,
                                                  bout, (float*)d_out, 512, 32000);
  } else {
    gemm_nt_k<<<dim3(500, 64), 256, 0, stream>>>(ws + OFF_DOUT, Wout, bout,
                                                 (float*)d_out, 512, 32000);
  }
}

// Round 12
// 3109.922 us; speedup vs baseline: 1.3992x; 1.2104x over previous
//
#include <hip/hip_runtime.h>
#include <math.h>

#define Bsz 32
#define Hd  512
#define SEQ 128
#define G4H 2048
#define BH  16384   // Bsz*Hd
#define BARSTRIDE 32

typedef __attribute__((ext_vector_type(8))) short bf16x8;
typedef __attribute__((ext_vector_type(4))) float f32x4;
typedef __attribute__((ext_vector_type(4))) unsigned short us4;

__device__ __forceinline__ void gload16(const void* g, void* l) {
  __builtin_amdgcn_global_load_lds(
      (const __attribute__((address_space(1))) unsigned int*)g,
      (__attribute__((address_space(3))) unsigned int*)l, 16, 0, 0);
}

// ---------------- weight pre-pack (R9 layout: [kk16][ks2 8][jj8]) ----------------
__global__ __launch_bounds__(256) void pack_w_k(const float* __restrict__ W,
                                                float* __restrict__ out) {
  __shared__ float Wl[8][512];
  const int blk = blockIdx.x, tid = threadIdx.x;
  #pragma unroll
  for (int r = 0; r < 8; ++r) {
    int j = ((r >> 1) << 9) + (blk << 1) + (r & 1);
    Wl[r][tid] = W[j * Hd + tid];
    Wl[r][tid + 256] = W[j * Hd + tid + 256];
  }
  __syncthreads();
  #pragma unroll
  for (int q = 0; q < 16; ++q) {
    int i = tid * 16 + q;
    int kk = i >> 8, rest = i & 255, ks2 = rest >> 3, jj = rest & 7;
    out[((size_t)blk << 12) + i] = Wl[jj][(ks2 << 4) + kk];
  }
}

__global__ __launch_bounds__(256) void bias_sum_k(const float* __restrict__ a,
                                                  const float* __restrict__ b,
                                                  float* __restrict__ out) {
  int i = blockIdx.x * 256 + threadIdx.x;
  if (i < G4H) out[i] = a[i] + b[i];
}

__global__ __launch_bounds__(256) void embed_k(const int* __restrict__ idx,
                                               const float* __restrict__ emb,
                                               float* __restrict__ out) {
  int t = blockIdx.x * 256 + threadIdx.x;
  int m = t >> 6, e4 = (t & 63) << 2;
  *(float4*)&out[(size_t)m * 256 + e4] =
      *(const float4*)&emb[(size_t)idx[m] * 256 + e4];
}

// ---------------- fp32 -> bf16 hi/lo split ----------------
__global__ __launch_bounds__(256) void split_k(const float* __restrict__ X,
                                               unsigned short* __restrict__ hi,
                                               unsigned short* __restrict__ lo) {
  int i = (blockIdx.x * 256 + threadIdx.x) << 2;
  float4 x = *(const float4*)&X[i];
  const float* xp = (const float*)&x;
  us4 h, l;
  #pragma unroll
  for (int e = 0; e < 4; ++e) {
    float v = xp[e];
    unsigned int u = __float_as_uint(v);
    unsigned int hr = (u + 0x7fffu + ((u >> 16) & 1u)) & 0xffff0000u;
    h[e] = (unsigned short)(hr >> 16);
    float rem = v - __uint_as_float(hr);
    unsigned int u2 = __float_as_uint(rem);
    l[e] = (unsigned short)((u2 + 0x7fffu + ((u2 >> 16) & 1u)) >> 16);
  }
  *(us4*)&hi[i] = h;
  *(us4*)&lo[i] = l;
}

// ---------------- fp32 NT GEMM (fallback only) ----------------
__global__ __launch_bounds__(256, 2)
void gemm_nt_k(const float* __restrict__ A, const float* __restrict__ Wt,
               const float* __restrict__ bias, float* __restrict__ C,
               int K, int ldc)
{
  __shared__ float As[32 * 68];
  __shared__ float Ws[32 * 68];
  const int tid = threadIdx.x;
  const int m0 = blockIdx.y << 6, n0 = blockIdx.x << 6;
  const int tn = tid & 15, tm = tid >> 4;
  const int lr = tid >> 2, lk = (tid & 3) << 3;
  float acc[4][4] = {};
  for (int kt = 0; kt < K; kt += 32) {
    #pragma unroll
    for (int i = 0; i < 2; ++i) {
      float4 a = *(const float4*)&A[(size_t)(m0 + lr) * K + kt + lk + (i << 2)];
      float4 w = *(const float4*)&Wt[(size_t)(n0 + lr) * K + kt + lk + (i << 2)];
      const float* ap = (const float*)&a;
      const float* wp = (const float*)&w;
      #pragma unroll
      for (int d = 0; d < 4; ++d) {
        As[(lk + (i << 2) + d) * 68 + lr] = ap[d];
        Ws[(lk + (i << 2) + d) * 68 + lr] = wp[d];
      }
    }
    __syncthreads();
    #pragma unroll 8
    for (int kk = 0; kk < 32; ++kk) {
      float4 av = *(const float4*)&As[kk * 68 + (tm << 2)];
      float4 wv = *(const float4*)&Ws[kk * 68 + (tn << 2)];
      const float* ap = (const float*)&av;
      const float* wp = (const float*)&wv;
      #pragma unroll
      for (int i = 0; i < 4; ++i)
        #pragma unroll
        for (int j = 0; j < 4; ++j)
          acc[i][j] += ap[i] * wp[j];
    }
    __syncthreads();
  }
  #pragma unroll
  for (int i = 0; i < 4; ++i) {
    float4 o;
    float* op = (float*)&o;
    #pragma unroll
    for (int j = 0; j < 4; ++j) op[j] = acc[i][j] + bias[n0 + (tn << 2) + j];
    *(float4*)&C[(size_t)(m0 + (tm << 2) + i) * ldc + n0 + (tn << 2)] = o;
  }
}

// ---------------- bf16 MFMA 3-term split GEMM (K, ldc parameterized) ----------------
__global__ __launch_bounds__(256)
void gemm_bfs_k(const unsigned short* __restrict__ Ahi,
                const unsigned short* __restrict__ Alo,
                const unsigned short* __restrict__ Bhi,
                const unsigned short* __restrict__ Blo,
                const float* __restrict__ bias,
                float* __restrict__ C, int K, int ldc)
{
  __shared__ unsigned short As[4096];   // [128][32]
  __shared__ unsigned short Bs[4096];   // [128][32]
  const int tid = threadIdx.x;
  const int m0 = blockIdx.x << 7, n0 = blockIdx.y << 7;
  const int lane = tid & 63, wave = tid >> 6;
  const int wr = wave >> 1, wc = wave & 1;
  const int srow = wave * 32 + (lane >> 2);
  const int sk = (lane & 3) << 3;
  const int ldse = wave * 1024 + lane * 8;
  const int fr = lane & 15, fk = (lane >> 4) << 3;

  f32x4 acc[4][4];
  #pragma unroll
  for (int a = 0; a < 4; ++a)
    #pragma unroll
    for (int b = 0; b < 4; ++b) acc[a][b] = (f32x4){0.f, 0.f, 0.f, 0.f};

  #pragma unroll 1
  for (int seg = 0; seg < 3; ++seg) {
    const unsigned short* Ab = (seg == 2) ? Alo : Ahi;
    const unsigned short* Bb = (seg == 1) ? Blo : Bhi;
    #pragma unroll 1
    for (int kt = 0; kt < K; kt += 32) {
      gload16(Ab + (size_t)(m0 + srow) * K + kt + sk, &As[ldse]);
      gload16(Ab + (size_t)(m0 + srow + 16) * K + kt + sk, &As[ldse + 512]);
      gload16(Bb + (size_t)(n0 + srow) * K + kt + sk, &Bs[ldse]);
      gload16(Bb + (size_t)(n0 + srow + 16) * K + kt + sk, &Bs[ldse + 512]);
      __syncthreads();
      bf16x8 af[4], bf[4];
      #pragma unroll
      for (int mf = 0; mf < 4; ++mf)
        af[mf] = *(const bf16x8*)&As[(wr * 64 + mf * 16 + fr) * 32 + fk];
      #pragma unroll
      for (int nf = 0; nf < 4; ++nf)
        bf[nf] = *(const bf16x8*)&Bs[(wc * 64 + nf * 16 + fr) * 32 + fk];
      #pragma unroll
      for (int mf = 0; mf < 4; ++mf)
        #pragma unroll
        for (int nf = 0; nf < 4; ++nf)
          acc[mf][nf] = __builtin_amdgcn_mfma_f32_16x16x32_bf16(af[mf], bf[nf],
                                                                acc[mf][nf], 0, 0, 0);
      __syncthreads();
    }
  }

  const int rgrp = (lane >> 4) << 2;
  #pragma unroll
  for (int nf = 0; nf < 4; ++nf) {
    int n = n0 + wc * 64 + nf * 16 + fr;
    float bn = bias[n];
    #pragma unroll
    for (int mf = 0; mf < 4; ++mf) {
      #pragma unroll
      for (int r = 0; r < 4; ++r) {
        int m = m0 + wr * 64 + mf * 16 + rgrp + r;
        C[(size_t)m * ldc + n] = acc[mf][nf][r] + bn;
      }
    }
  }
}

// ---------------- R9 spread-flag sync (one cacheline per block) ----------------
__device__ __forceinline__ void pollwait(const int* arr, int target) {
  const int tid = threadIdx.x;
  if (tid < 64) {
    const int* p0 = &arr[tid * BARSTRIDE];
    const int* p1 = &arr[(tid + 64) * BARSTRIDE];
    const int* p2 = &arr[(tid + 128) * BARSTRIDE];
    const int* p3 = &arr[(tid + 192) * BARSTRIDE];
    for (;;) {
      int a = __hip_atomic_load(p0, __ATOMIC_RELAXED, __HIP_MEMORY_SCOPE_AGENT);
      int b = __hip_atomic_load(p1, __ATOMIC_RELAXED, __HIP_MEMORY_SCOPE_AGENT);
      int c = __hip_atomic_load(p2, __ATOMIC_RELAXED, __HIP_MEMORY_SCOPE_AGENT);
      int d = __hip_atomic_load(p3, __ATOMIC_RELAXED, __HIP_MEMORY_SCOPE_AGENT);
      if (__all(min(min(a, b), min(c, d)) >= target)) break;
      __builtin_amdgcn_s_sleep(1);
    }
  }
  __syncthreads();
}

// ---------------- persistent LSTM: R9 structure + fused bf16 split of dec_out ----------------
__global__ __launch_bounds__(256, 1)
void lstm_seq_k(const float* __restrict__ w0p,  // packed Whh0  [256][4096]
                const float* __restrict__ w1ap, // packed Wih1
                const float* __restrict__ w1bp, // packed Whh1
                const float* __restrict__ x0pre,// [B*SEQ][2048] input gates (+biases)
                const float* __restrict__ bias1,// [2048] bih1+bhh1
                float* __restrict__ h0steps, float* __restrict__ h1steps,
                const float* __restrict__ h0init, const float* __restrict__ h1init,
                const float* __restrict__ c0init, const float* __restrict__ c1init,
                float* __restrict__ c0fin, float* __restrict__ c1fin,
                float* __restrict__ dec_out,          // fp32 (fallback) or nullptr
                unsigned short* __restrict__ dechi,   // bf16 hi (mfma) or nullptr
                unsigned short* __restrict__ declo,   // bf16 lo
                int* __restrict__ flag)
{
  __shared__ float w0s[4096], w1as[4096], w1bs[4096];
  __shared__ float rbuf[16384];   // [0:8192)=L0, [8192:16384)=L1
  __shared__ float gbuf[512];     // [0:256)=L0 gates, [256:512)=L1

  const int blk = blockIdx.x, tid = threadIdx.x;
  const int bg = tid & 7, ks = tid >> 3;
  const int n0 = blk << 1;

  // stage all three packed weight panels once
  for (int i = tid * 4; i < 4096; i += 1024) {
    *(float4*)&w0s[i]  = *(const float4*)&w0p[((size_t)blk << 12) + i];
    *(float4*)&w1as[i] = *(const float4*)&w1ap[((size_t)blk << 12) + i];
    *(float4*)&w1bs[i] = *(const float4*)&w1bp[((size_t)blk << 12) + i];
  }

  // loop-invariant per-thread state
  const int half = (tid >> 6) & 1;               // wave0 -> L0 pointwise, wave1 -> L1
  const int pr = tid & 63;
  const int cc_ = pr & 1, b2_ = pr >> 1, nn_ = n0 + cc_;
  float creg = 0.f;
  if (tid < 128) creg = (half ? c1init : c0init)[b2_ * Hd + nn_];
  const int rcol = tid & 7, rb = tid >> 3, rbgr = rb >> 2, rbi = rb & 3;
  const int rj = ((rcol >> 1) << 9) + n0 + (rcol & 1);
  const float bv = bias1[rj];
  const float* xbase = x0pre + (size_t)rb * SEQ * G4H + rj;
  __syncthreads();

  #pragma unroll 1
  for (int u = 0; u <= SEQ; ++u) {
    const bool doL0 = (u < SEQ), doL1 = (u >= 1);
    const int wbase = ks << 3;

    // x prefetch before the wait (static address; latency hides under poll)
    float xv = doL0 ? xbase[(size_t)u * G4H] : 0.f;

    if (u > 0) pollwait(flag, u);   // all of super-step u-1's outputs visible

    // ---- h loads (coalesced float4, fresh per-step addresses) ----
    float hA[4][16];
    {
      const float* h0p = (u == 0) ? h0init : h0steps + (size_t)(u - 1) * BH;
      #pragma unroll
      for (int bi = 0; bi < 4; ++bi) {
        int b = (bg << 2) + bi;
        #pragma unroll
        for (int q = 0; q < 4; ++q) {
          float4 t = *(const float4*)&h0p[b * Hd + (ks << 4) + (q << 2)];
          hA[bi][q * 4 + 0] = t.x; hA[bi][q * 4 + 1] = t.y;
          hA[bi][q * 4 + 2] = t.z; hA[bi][q * 4 + 3] = t.w;
        }
      }
    }
    float hB[4][16];
    if (doL1) {
      const float* h1p = (u == 1) ? h1init : h1steps + (size_t)(u - 2) * BH;
      #pragma unroll
      for (int bi = 0; bi < 4; ++bi) {
        int b = (bg << 2) + bi;
        #pragma unroll
        for (int q = 0; q < 4; ++q) {
          float4 t = *(const float4*)&h1p[b * Hd + (ks << 4) + (q << 2)];
          hB[bi][q * 4 + 0] = t.x; hB[bi][q * 4 + 1] = t.y;
          hB[bi][q * 4 + 2] = t.z; hB[bi][q * 4 + 3] = t.w;
        }
      }
    }

    __attribute__((aligned(16))) float acc0[8][4];
    __attribute__((aligned(16))) float acc1[8][4];
    #pragma unroll
    for (int jj = 0; jj < 8; ++jj)
      #pragma unroll
      for (int bi = 0; bi < 4; ++bi) { acc0[jj][bi] = 0.f; acc1[jj][bi] = 0.f; }

    if (doL0) {
      #pragma unroll
      for (int kk = 0; kk < 16; ++kk) {          // Whh0 . hA
        float4 wlo = *(const float4*)&w0s[(kk << 8) + wbase];
        float4 whi = *(const float4*)&w0s[(kk << 8) + wbase + 4];
        const float* wl = (const float*)&wlo;
        const float* wh = (const float*)&whi;
        #pragma unroll
        for (int jj = 0; jj < 4; ++jj)
          #pragma unroll
          for (int bi = 0; bi < 4; ++bi) {
            acc0[jj][bi]     += wl[jj] * hA[bi][kk];
            acc0[4 + jj][bi] += wh[jj] * hA[bi][kk];
          }
      }
    }
    if (doL1) {
      #pragma unroll
      for (int kk = 0; kk < 16; ++kk) {          // Wih1 . hA
        float4 wlo = *(const float4*)&w1as[(kk << 8) + wbase];
        float4 whi = *(const float4*)&w1as[(kk << 8) + wbase + 4];
        const float* wl = (const float*)&wlo;
        const float* wh = (const float*)&whi;
        #pragma unroll
        for (int jj = 0; jj < 4; ++jj)
          #pragma unroll
          for (int bi = 0; bi < 4; ++bi) {
            acc1[jj][bi]     += wl[jj] * hA[bi][kk];
            acc1[4 + jj][bi] += wh[jj] * hA[bi][kk];
          }
      }
      #pragma unroll
      for (int kk = 0; kk < 16; ++kk) {          // Whh1 . hB
        float4 wlo = *(const float4*)&w1bs[(kk << 8) + wbase];
        float4 whi = *(const float4*)&w1bs[(kk << 8) + wbase + 4];
        const float* wl = (const float*)&wlo;
        const float* wh = (const float*)&whi;
        #pragma unroll
        for (int jj = 0; jj < 4; ++jj)
          #pragma unroll
          for (int bi = 0; bi < 4; ++bi) {
            acc1[jj][bi]     += wl[jj] * hB[bi][kk];
            acc1[4 + jj][bi] += wh[jj] * hB[bi][kk];
          }
      }
    }

    // ---- both reductions through doubled rbuf, one barrier pair ----
    if (doL0) {
      #pragma unroll
      for (int jj = 0; jj < 8; ++jj)
        *(float4*)&rbuf[(ks << 8) + (bg << 5) + ((jj ^ bg) << 2)] = *(const float4*)acc0[jj];
    }
    if (doL1) {
      #pragma unroll
      for (int jj = 0; jj < 8; ++jj)
        *(float4*)&rbuf[8192 + (ks << 8) + (bg << 5) + ((jj ^ bg) << 2)] = *(const float4*)acc1[jj];
    }
    __syncthreads();
    if (doL0) {
      float s = xv;
      #pragma unroll 8
      for (int k2 = 0; k2 < 32; ++k2)
        s += rbuf[(k2 << 8) + (rbgr << 5) + ((rcol ^ rbgr) << 2) + rbi];
      gbuf[(rcol << 5) + rb] = s;
    }
    if (doL1) {
      float s = bv;
      #pragma unroll 8
      for (int k2 = 0; k2 < 32; ++k2)
        s += rbuf[8192 + (k2 << 8) + (rbgr << 5) + ((rcol ^ rbgr) << 2) + rbi];
      gbuf[256 + (rcol << 5) + rb] = s;
    }
    __syncthreads();

    // ---- pointwise: wave0 -> L0, wave1 -> L1 (parallel, coalesced stores) ----
    if (tid < 64 && doL0) {
      float gi = gbuf[((0 + cc_) << 5) + b2_];
      float gf = gbuf[((2 + cc_) << 5) + b2_];
      float gg = gbuf[((4 + cc_) << 5) + b2_];
      float go = gbuf[((6 + cc_) << 5) + b2_];
      float i_ = 1.f / (1.f + expf(-gi));
      float f_ = 1.f / (1.f + expf(-gf));
      float o_ = 1.f / (1.f + expf(-go));
      float g_ = tanhf(gg);
      float cn = f_ * creg + i_ * g_;
      float hn = o_ * tanhf(cn);
      creg = cn;
      __hip_atomic_store(&h0steps[(size_t)u * BH + b2_ * Hd + nn_], hn,
                         __ATOMIC_RELAXED, __HIP_MEMORY_SCOPE_AGENT);
    } else if (tid >= 64 && tid < 128 && doL1) {
      const int t = u - 1;
      float gi = gbuf[256 + ((0 + cc_) << 5) + b2_];
      float gf = gbuf[256 + ((2 + cc_) << 5) + b2_];
      float gg = gbuf[256 + ((4 + cc_) << 5) + b2_];
      float go = gbuf[256 + ((6 + cc_) << 5) + b2_];
      float i_ = 1.f / (1.f + expf(-gi));
      float f_ = 1.f / (1.f + expf(-gf));
      float o_ = 1.f / (1.f + expf(-go));
      float g_ = tanhf(gg);
      float cn = f_ * creg + i_ * g_;
      float hn = o_ * tanhf(cn);
      creg = cn;
      __hip_atomic_store(&h1steps[(size_t)t * BH + b2_ * Hd + nn_], hn,
                         __ATOMIC_RELAXED, __HIP_MEMORY_SCOPE_AGENT);
      if (dechi) {
        // fused RNE bf16 hi/lo split (same math as split_k)
        unsigned int uu = __float_as_uint(hn);
        unsigned int hr = (uu + 0x7fffu + ((uu >> 16) & 1u)) & 0xffff0000u;
        float rem = hn - __uint_as_float(hr);
        unsigned int u2 = __float_as_uint(rem);
        size_t mo = ((size_t)b2_ * SEQ + t) * Hd + nn_;
        dechi[mo] = (unsigned short)(hr >> 16);
        declo[mo] = (unsigned short)((u2 + 0x7fffu + ((u2 >> 16) & 1u)) >> 16);
      } else if (dec_out) {
        dec_out[((size_t)b2_ * SEQ + t) * Hd + nn_] = hn;
      }
    }

    // drain every wave's write-through stores, then single publish
    asm volatile("s_waitcnt vmcnt(0)" ::: "memory");
    __syncthreads();
    if (tid == 0)
      __hip_atomic_store(&flag[blk * BARSTRIDE], u + 1,
                         __ATOMIC_RELAXED, __HIP_MEMORY_SCOPE_AGENT);
  }

  // final c handoff
  if (tid < 128) {
    float* cf = half ? c1fin : c0fin;
    cf[b2_ * Hd + nn_] = creg;
  }
}

// ---------------- host ----------------
extern "C" void kernel_launch(void* const* d_in, const int* in_sizes, int n_in,
                              void* d_out, int out_size, void* d_ws, size_t ws_size,
                              hipStream_t stream) {
  const int*   src  = (const int*)d_in[0];
  const int*   tgt  = (const int*)d_in[1];
  const float* emb  = (const float*)d_in[2];
  const float* Wout = (const float*)d_in[3];
  const float* bout = (const float*)d_in[4];
  const float* eWih0 = (const float*)d_in[5];
  const float* eWhh0 = (const float*)d_in[6];
  const float* ebih0 = (const float*)d_in[7];
  const float* ebhh0 = (const float*)d_in[8];
  const float* eWih1 = (const float*)d_in[9];
  const float* eWhh1 = (const float*)d_in[10];
  const float* ebih1 = (const float*)d_in[11];
  const float* ebhh1 = (const float*)d_in[12];
  const float* dWih0 = (const float*)d_in[13];
  const float* dWhh0 = (const float*)d_in[14];
  const float* dbih0 = (const float*)d_in[15];
  const float* dbhh0 = (const float*)d_in[16];
  const float* dWih1 = (const float*)d_in[17];
  const float* dWhh1 = (const float*)d_in[18];
  const float* dbih1 = (const float*)d_in[19];
  const float* dbhh1 = (const float*)d_in[20];

  float* ws = (float*)d_ws;
  char*  wsb = (char*)d_ws;
  // float offsets
  const size_t OFF_EMB  = 0;          // dead after input gemms
  const size_t OFF_X0   = 1048576;
  const size_t OFF_W0E  = 9437184;
  const size_t OFF_W1AE = 10485760;
  const size_t OFF_W1BE = 11534336;
  const size_t OFF_W0D  = 12582912;
  const size_t OFF_W1AD = 13631488;
  const size_t OFF_W1BD = 14680064;
  const size_t OFF_BS0E = 15728640;
  const size_t OFF_B1E  = 15730688;
  const size_t OFF_BS0D = 15732736;
  const size_t OFF_B1D  = 15734784;
  const size_t OFF_H0   = 15736832;   // 128*BH (per-step h0 slots)
  const size_t OFF_H1   = 17833984;   // 128*BH
  const size_t OFF_C0   = 19931136;   // BH (enc-final c0 -> dec init)
  const size_t OFF_C1   = 19947520;   // BH
  const size_t OFF_Z    = 19963904;   // BH zeros
  const size_t OFF_BAR  = 19980288;   // 2 x 8192 ints (enc flag, dec flag), 128B spread
  const size_t OFF_DOUT = 20013056;   // 2,097,152 f (fallback only)
  // bf16 overlays
  unsigned short* Ahi = (unsigned short*)(wsb + 88440832);   // 4096*512 (dec_out hi)
  unsigned short* Alo = (unsigned short*)(wsb + 92635136);   // 4096*512 (dec_out lo)
  unsigned short* Bhi = (unsigned short*)(wsb + 0);          // 32000*512 (dead low region)
  unsigned short* Blo = (unsigned short*)(wsb + 32768000);
  // input-gemm overlays: Ehi/Elo in DOUT region (dead in mfma path);
  // WIhi/WIlo in the Ahi region (dead until dec LSTM writes it).
  unsigned short* Ehi  = (unsigned short*)(wsb + 80052224);  // 4096*256
  unsigned short* Elo  = (unsigned short*)(wsb + 82149376);
  unsigned short* WIhi = (unsigned short*)(wsb + 88440832);  // 2048*256 (reused enc/dec)
  unsigned short* WIlo = (unsigned short*)(wsb + 89489408);
  const bool use_mfma = ws_size >= 96829440ull;

  int* eflag = (int*)(ws + OFF_BAR);
  int* dflag = eflag + 8192;

  // pack weights + bias sums
  pack_w_k<<<256, 256, 0, stream>>>(eWhh0, ws + OFF_W0E);
  pack_w_k<<<256, 256, 0, stream>>>(eWih1, ws + OFF_W1AE);
  pack_w_k<<<256, 256, 0, stream>>>(eWhh1, ws + OFF_W1BE);
  pack_w_k<<<256, 256, 0, stream>>>(dWhh0, ws + OFF_W0D);
  pack_w_k<<<256, 256, 0, stream>>>(dWih1, ws + OFF_W1AD);
  pack_w_k<<<256, 256, 0, stream>>>(dWhh1, ws + OFF_W1BD);
  bias_sum_k<<<8, 256, 0, stream>>>(ebih0, ebhh0, ws + OFF_BS0E);
  bias_sum_k<<<8, 256, 0, stream>>>(ebih1, ebhh1, ws + OFF_B1E);
  bias_sum_k<<<8, 256, 0, stream>>>(dbih0, dbhh0, ws + OFF_BS0D);
  bias_sum_k<<<8, 256, 0, stream>>>(dbih1, dbhh1, ws + OFF_B1D);

  // zero zbuf + both spread-flag arrays every call (graph replay safe)
  hipMemsetAsync(ws + OFF_Z, 0, (size_t)(BH + 16384) * 4, stream);

  // ---- encoder ----
  embed_k<<<1024, 256, 0, stream>>>(src, emb, ws + OFF_EMB);
  if (use_mfma) {
    split_k<<<1024, 256, 0, stream>>>(ws + OFF_EMB, Ehi, Elo);
    split_k<<<512, 256, 0, stream>>>(eWih0, WIhi, WIlo);
    gemm_bfs_k<<<dim3(32, 16), 256, 0, stream>>>(Ehi, Elo, WIhi, WIlo,
                                                 ws + OFF_BS0E, ws + OFF_X0, 256, 2048);
  } else {
    gemm_nt_k<<<dim3(32, 64), 256, 0, stream>>>(ws + OFF_EMB, eWih0, ws + OFF_BS0E,
                                                ws + OFF_X0, 256, 2048);
  }
  lstm_seq_k<<<256, 256, 0, stream>>>(ws + OFF_W0E, ws + OFF_W1AE, ws + OFF_W1BE,
                                      ws + OFF_X0, ws + OFF_B1E,
                                      ws + OFF_H0, ws + OFF_H1,
                                      ws + OFF_Z, ws + OFF_Z,      // h inits (zeros)
                                      ws + OFF_Z, ws + OFF_Z,      // c inits (zeros)
                                      ws + OFF_C0, ws + OFF_C1,    // c finals
                                      nullptr, nullptr, nullptr, eflag);

  // ---- decoder (inits = encoder finals) ----
  embed_k<<<1024, 256, 0, stream>>>(tgt, emb, ws + OFF_EMB);
  if (use_mfma) {
    split_k<<<1024, 256, 0, stream>>>(ws + OFF_EMB, Ehi, Elo);
    split_k<<<512, 256, 0, stream>>>(dWih0, WIhi, WIlo);
    gemm_bfs_k<<<dim3(32, 16), 256, 0, stream>>>(Ehi, Elo, WIhi, WIlo,
                                                 ws + OFF_BS0D, ws + OFF_X0, 256, 2048);
  } else {
    gemm_nt_k<<<dim3(32, 64), 256, 0, stream>>>(ws + OFF_EMB, dWih0, ws + OFF_BS0D,
                                                ws + OFF_X0, 256, 2048);
  }
  lstm_seq_k<<<256, 256, 0, stream>>>(ws + OFF_W0D, ws + OFF_W1AD, ws + OFF_W1BD,
                                      ws + OFF_X0, ws + OFF_B1D,
                                      ws + OFF_H0, ws + OFF_H1,
                                      ws + OFF_H0 + (size_t)127 * BH,
                                      ws + OFF_H1 + (size_t)127 * BH,
                                      ws + OFF_C0, ws + OFF_C1,
                                      ws + OFF_C0, ws + OFF_C1,
                                      use_mfma ? nullptr : ws + OFF_DOUT,
                                      use_mfma ? Ahi : nullptr,
                                      use_mfma ? Alo : nullptr, dflag);

  // ---- vocab projection ----
  if (use_mfma) {
    split_k<<<16000, 256, 0, stream>>>(Wout, Bhi, Blo);   // overlays dead low region
    gemm_bfs_k<<<dim3(32, 250), 256, 0, stream>>>(Ahi, Alo, Bhi, Blo,
                                                  bout, (float*)d_out, 512, 32000);
  } else {
    gemm_nt_k<<<dim3(500, 64), 256, 0, stream>>>(ws + OFF_DOUT, Wout, bout,
                                                 (float*)d_out, 512, 32000);
  }
}

// Round 13
// 2368.387 us; speedup vs baseline: 1.8373x; 1.3131x over previous
//
#include <hip/hip_runtime.h>
#include <math.h>

#define Bsz 32
#define Hd  512
#define SEQ 128
#define G4H 2048
#define BH  16384
#define BARSTRIDE 32
#define SLOT 16384   // 32*512 ushorts per h step-slot

typedef __attribute__((ext_vector_type(8))) short bf16x8;
typedef __attribute__((ext_vector_type(4))) float f32x4;
typedef __attribute__((ext_vector_type(4))) unsigned short us4;

__device__ __forceinline__ void gload16(const void* g, void* l) {
  __builtin_amdgcn_global_load_lds(
      (const __attribute__((address_space(1))) unsigned int*)g,
      (__attribute__((address_space(3))) unsigned int*)l, 16, 0, 0);
}

__global__ __launch_bounds__(256) void bias_sum_k(const float* __restrict__ a,
                                                  const float* __restrict__ b,
                                                  float* __restrict__ out) {
  int i = blockIdx.x * 256 + threadIdx.x;
  if (i < G4H) out[i] = a[i] + b[i];
}

__global__ __launch_bounds__(256) void embed_k(const int* __restrict__ idx,
                                               const float* __restrict__ emb,
                                               float* __restrict__ out) {
  int t = blockIdx.x * 256 + threadIdx.x;
  int m = t >> 6, e4 = (t & 63) << 2;
  *(float4*)&out[(size_t)m * 256 + e4] =
      *(const float4*)&emb[(size_t)idx[m] * 256 + e4];
}

// ---------------- fp32 -> bf16 hi/lo split ----------------
__global__ __launch_bounds__(256) void split_k(const float* __restrict__ X,
                                               unsigned short* __restrict__ hi,
                                               unsigned short* __restrict__ lo) {
  int i = (blockIdx.x * 256 + threadIdx.x) << 2;
  float4 x = *(const float4*)&X[i];
  const float* xp = (const float*)&x;
  us4 h, l;
  #pragma unroll
  for (int e = 0; e < 4; ++e) {
    float v = xp[e];
    unsigned int u = __float_as_uint(v);
    unsigned int hr = (u + 0x7fffu + ((u >> 16) & 1u)) & 0xffff0000u;
    h[e] = (unsigned short)(hr >> 16);
    float rem = v - __uint_as_float(hr);
    unsigned int u2 = __float_as_uint(rem);
    l[e] = (unsigned short)((u2 + 0x7fffu + ((u2 >> 16) & 1u)) >> 16);
  }
  *(us4*)&hi[i] = h;
  *(us4*)&lo[i] = l;
}

// ---------------- weight pack: bf16 hi/lo in MFMA B-fragment layout ----------------
// Block blk (128 blocks, 4 cells each): out[blk][half][kf16][lane64][e8]:
// value = W_half[jj = l&15 -> j=(jj>>2)*512 + blk*4 + (jj&3)][kf*32 + (l>>4)*8 + e]
__global__ __launch_bounds__(256) void pack_wbf_k(const float* __restrict__ W,
                                                  unsigned short* __restrict__ out) {
  __shared__ float Wl[16][512];
  const int blk = blockIdx.x, tid = threadIdx.x;
  #pragma unroll
  for (int r = 0; r < 16; ++r) {
    int j = (r >> 2) * 512 + blk * 4 + (r & 3);
    Wl[r][tid]       = W[(size_t)j * 512 + tid];
    Wl[r][tid + 256] = W[(size_t)j * 512 + tid + 256];
  }
  __syncthreads();
  for (int idx = tid; idx < 8192; idx += 256) {
    int kf = idx >> 9, l = (idx >> 3) & 63, e = idx & 7;
    int col = l & 15;
    int kpos = (kf << 5) + ((l >> 4) << 3) + e;
    float v = Wl[col][kpos];
    unsigned int uu = __float_as_uint(v);
    unsigned int hr = (uu + 0x7fffu + ((uu >> 16) & 1u)) & 0xffff0000u;
    float rem = v - __uint_as_float(hr);
    unsigned int u2 = __float_as_uint(rem);
    out[(size_t)blk * 16384 + idx] = (unsigned short)(hr >> 16);
    out[(size_t)blk * 16384 + 8192 + idx] =
        (unsigned short)((u2 + 0x7fffu + ((u2 >> 16) & 1u)) >> 16);
  }
}

// ---------------- bf16 MFMA 3-term split GEMM (amode: A-row remap for h1steps) ----------------
__global__ __launch_bounds__(256)
void gemm_bfs_k(const unsigned short* __restrict__ Ahi,
                const unsigned short* __restrict__ Alo,
                const unsigned short* __restrict__ Bhi,
                const unsigned short* __restrict__ Blo,
                const float* __restrict__ bias,
                float* __restrict__ C, int K, int ldc, int amode)
{
  __shared__ unsigned short As[4096];
  __shared__ unsigned short Bs[4096];
  const int tid = threadIdx.x;
  const int m0 = blockIdx.x << 7, n0 = blockIdx.y << 7;
  const int lane = tid & 63, wave = tid >> 6;
  const int wr = wave >> 1, wc = wave & 1;
  const int srow = wave * 32 + (lane >> 2);
  const int sk = (lane & 3) << 3;
  const int ldse = wave * 1024 + lane * 8;
  const int fr = lane & 15, fk = (lane >> 4) << 3;

  const int r1 = m0 + srow, r2 = m0 + srow + 16;
  const size_t ra1 = amode ? ((size_t)(r1 & 127) * 32 + (r1 >> 7)) * 512 : (size_t)r1 * K;
  const size_t ra2 = amode ? ((size_t)(r2 & 127) * 32 + (r2 >> 7)) * 512 : (size_t)r2 * K;

  f32x4 acc[4][4];
  #pragma unroll
  for (int a = 0; a < 4; ++a)
    #pragma unroll
    for (int b = 0; b < 4; ++b) acc[a][b] = (f32x4){0.f, 0.f, 0.f, 0.f};

  #pragma unroll 1
  for (int seg = 0; seg < 3; ++seg) {
    const unsigned short* Ab = (seg == 2) ? Alo : Ahi;
    const unsigned short* Bb = (seg == 1) ? Blo : Bhi;
    #pragma unroll 1
    for (int kt = 0; kt < K; kt += 32) {
      gload16(Ab + ra1 + kt + sk, &As[ldse]);
      gload16(Ab + ra2 + kt + sk, &As[ldse + 512]);
      gload16(Bb + (size_t)(n0 + srow) * K + kt + sk, &Bs[ldse]);
      gload16(Bb + (size_t)(n0 + srow + 16) * K + kt + sk, &Bs[ldse + 512]);
      __syncthreads();
      bf16x8 af[4], bf[4];
      #pragma unroll
      for (int mf = 0; mf < 4; ++mf)
        af[mf] = *(const bf16x8*)&As[(wr * 64 + mf * 16 + fr) * 32 + fk];
      #pragma unroll
      for (int nf = 0; nf < 4; ++nf)
        bf[nf] = *(const bf16x8*)&Bs[(wc * 64 + nf * 16 + fr) * 32 + fk];
      #pragma unroll
      for (int mf = 0; mf < 4; ++mf)
        #pragma unroll
        for (int nf = 0; nf < 4; ++nf)
          acc[mf][nf] = __builtin_amdgcn_mfma_f32_16x16x32_bf16(af[mf], bf[nf],
                                                                acc[mf][nf], 0, 0, 0);
      __syncthreads();
    }
  }

  const int rgrp = (lane >> 4) << 2;
  #pragma unroll
  for (int nf = 0; nf < 4; ++nf) {
    int n = n0 + wc * 64 + nf * 16 + fr;
    float bn = bias[n];
    #pragma unroll
    for (int mf = 0; mf < 4; ++mf) {
      #pragma unroll
      for (int r = 0; r < 4; ++r) {
        int m = m0 + wr * 64 + mf * 16 + rgrp + r;
        C[(size_t)m * ldc + n] = acc[mf][nf][r] + bn;
      }
    }
  }
}

// ---------------- spread-flag sync (128 blocks, 1 cacheline each) ----------------
__device__ __forceinline__ void pollwait(const int* arr, int target) {
  const int tid = threadIdx.x;
  if (tid < 64) {
    const int* p0 = &arr[tid * BARSTRIDE];
    const int* p1 = &arr[(tid + 64) * BARSTRIDE];
    for (;;) {
      int a = __hip_atomic_load(p0, __ATOMIC_RELAXED, __HIP_MEMORY_SCOPE_AGENT);
      int b = __hip_atomic_load(p1, __ATOMIC_RELAXED, __HIP_MEMORY_SCOPE_AGENT);
      if (__all(min(a, b) >= target)) break;
      __builtin_amdgcn_s_sleep(1);
    }
  }
  __syncthreads();
}

// ---------------- persistent LSTM: MFMA recurrent matmul, 128 blocks x 4 cells ----------------
// Same sync protocol as R9/R12: one pollwait(flag,u), one publish(flag=u+1) per super-step.
// h kept as bf16 hi/lo slot arrays [128][32][512]; 3-term split matmul.
__global__ __launch_bounds__(256, 1)
void lstm_seq_k(const unsigned short* __restrict__ pw0,   // Whh0 pack [128][2][8192]
                const unsigned short* __restrict__ pw1a,  // Wih1 pack
                const unsigned short* __restrict__ pw1b,  // Whh1 pack
                const float* __restrict__ x0pre,          // [B*SEQ][2048]
                const float* __restrict__ bias1,          // [2048]
                unsigned short* __restrict__ h0hi, unsigned short* __restrict__ h0lo,
                unsigned short* __restrict__ h1hi, unsigned short* __restrict__ h1lo,
                const unsigned short* __restrict__ h0ihi, const unsigned short* __restrict__ h0ilo,
                const unsigned short* __restrict__ h1ihi, const unsigned short* __restrict__ h1ilo,
                const float* __restrict__ c0init, const float* __restrict__ c1init,
                float* __restrict__ c0fin, float* __restrict__ c1fin,
                int* __restrict__ flag)
{
  __shared__ unsigned short wlds[49152];  // 3 mats x [half2][kf16][lane64][e8]
  __shared__ float gpart[6144];           // [mat3][wave4][col16][b32]
  __shared__ float gx[512];               // [col16][b32]
  __shared__ unsigned short hstage[512];  // [layer2][hl2][b32][cl4]

  const int blk = blockIdx.x, tid = threadIdx.x;
  const int w = tid >> 6, lane = tid & 63;
  const int fr = lane & 15, fgk = (lane >> 4) << 3;

  // stage 3 packed weight mats (32 KB each)
  {
    const uint4* s0 = (const uint4*)(pw0 + (size_t)blk * 16384);
    const uint4* s1 = (const uint4*)(pw1a + (size_t)blk * 16384);
    const uint4* s2 = (const uint4*)(pw1b + (size_t)blk * 16384);
    uint4* d = (uint4*)wlds;
    for (int i = tid; i < 2048; i += 256) {
      d[i] = s0[i]; d[2048 + i] = s1[i]; d[4096 + i] = s2[i];
    }
  }

  // pointwise invariants: tid<128 -> L0 lane (cl,b2); tid>=128 -> L1 lane
  const int cl = (tid >> 5) & 3, b2 = tid & 31;
  const int nn = blk * 4 + cl;
  float creg, bv0 = 0.f, bv1 = 0.f, bv2 = 0.f, bv3 = 0.f;
  if (tid < 128) {
    creg = c0init[b2 * 512 + nn];
  } else {
    creg = c1init[b2 * 512 + nn];
    bv0 = bias1[nn]; bv1 = bias1[512 + nn];
    bv2 = bias1[1024 + nn]; bv3 = bias1[1536 + nn];
  }
  const int xcol = tid & 15, xb = tid >> 4;
  const int xj = (xcol >> 2) * 512 + blk * 4 + (xcol & 3);
  __syncthreads();

  #pragma unroll 1
  for (int u = 0; u <= SEQ; ++u) {
    const bool doL0 = (u < SEQ), doL1 = (u >= 1);

    // x prefetch before the wait
    float xv0 = 0.f, xv1 = 0.f;
    if (doL0) {
      xv0 = x0pre[((size_t)xb * SEQ + u) * G4H + xj];
      xv1 = x0pre[((size_t)(xb + 16) * SEQ + u) * G4H + xj];
    }

    if (u > 0) pollwait(flag, u);

    if (doL0) { gx[xcol * 32 + xb] = xv0; gx[xcol * 32 + xb + 16] = xv1; }

    const unsigned short* hAh = (u == 0) ? h0ihi : h0hi + (size_t)(u - 1) * SLOT;
    const unsigned short* hAl = (u == 0) ? h0ilo : h0lo + (size_t)(u - 1) * SLOT;
    const unsigned short* hBh = (u <= 1) ? h1ihi : h1hi + (size_t)(u - 2) * SLOT;
    const unsigned short* hBl = (u <= 1) ? h1ilo : h1lo + (size_t)(u - 2) * SLOT;

    f32x4 acc[3][2];
    #pragma unroll
    for (int m = 0; m < 3; ++m) {
      acc[m][0] = (f32x4){0.f, 0.f, 0.f, 0.f};
      acc[m][1] = (f32x4){0.f, 0.f, 0.f, 0.f};
    }

    #pragma unroll
    for (int q = 0; q < 4; ++q) {
      const int kf = (w << 2) + q;
      const int ko = (kf << 5) + fgk;
      const int wko = (kf << 9) + lane * 8;
      bf16x8 ah0 = *(const bf16x8*)&hAh[(size_t)fr * 512 + ko];
      bf16x8 al0 = *(const bf16x8*)&hAl[(size_t)fr * 512 + ko];
      bf16x8 ah1 = *(const bf16x8*)&hAh[(size_t)(fr + 16) * 512 + ko];
      bf16x8 al1 = *(const bf16x8*)&hAl[(size_t)(fr + 16) * 512 + ko];
      if (doL0) {
        bf16x8 bh = *(const bf16x8*)&wlds[wko];
        bf16x8 bl = *(const bf16x8*)&wlds[8192 + wko];
        acc[0][0] = __builtin_amdgcn_mfma_f32_16x16x32_bf16(ah0, bh, acc[0][0], 0, 0, 0);
        acc[0][0] = __builtin_amdgcn_mfma_f32_16x16x32_bf16(ah0, bl, acc[0][0], 0, 0, 0);
        acc[0][0] = __builtin_amdgcn_mfma_f32_16x16x32_bf16(al0, bh, acc[0][0], 0, 0, 0);
        acc[0][1] = __builtin_amdgcn_mfma_f32_16x16x32_bf16(ah1, bh, acc[0][1], 0, 0, 0);
        acc[0][1] = __builtin_amdgcn_mfma_f32_16x16x32_bf16(ah1, bl, acc[0][1], 0, 0, 0);
        acc[0][1] = __builtin_amdgcn_mfma_f32_16x16x32_bf16(al1, bh, acc[0][1], 0, 0, 0);
      }
      if (doL1) {
        bf16x8 bh = *(const bf16x8*)&wlds[16384 + wko];
        bf16x8 bl = *(const bf16x8*)&wlds[16384 + 8192 + wko];
        acc[1][0] = __builtin_amdgcn_mfma_f32_16x16x32_bf16(ah0, bh, acc[1][0], 0, 0, 0);
        acc[1][0] = __builtin_amdgcn_mfma_f32_16x16x32_bf16(ah0, bl, acc[1][0], 0, 0, 0);
        acc[1][0] = __builtin_amdgcn_mfma_f32_16x16x32_bf16(al0, bh, acc[1][0], 0, 0, 0);
        acc[1][1] = __builtin_amdgcn_mfma_f32_16x16x32_bf16(ah1, bh, acc[1][1], 0, 0, 0);
        acc[1][1] = __builtin_amdgcn_mfma_f32_16x16x32_bf16(ah1, bl, acc[1][1], 0, 0, 0);
        acc[1][1] = __builtin_amdgcn_mfma_f32_16x16x32_bf16(al1, bh, acc[1][1], 0, 0, 0);
        bf16x8 ch0 = *(const bf16x8*)&hBh[(size_t)fr * 512 + ko];
        bf16x8 cl0 = *(const bf16x8*)&hBl[(size_t)fr * 512 + ko];
        bf16x8 ch1 = *(const bf16x8*)&hBh[(size_t)(fr + 16) * 512 + ko];
        bf16x8 cl1 = *(const bf16x8*)&hBl[(size_t)(fr + 16) * 512 + ko];
        bf16x8 dh = *(const bf16x8*)&wlds[32768 + wko];
        bf16x8 dl = *(const bf16x8*)&wlds[32768 + 8192 + wko];
        acc[2][0] = __builtin_amdgcn_mfma_f32_16x16x32_bf16(ch0, dh, acc[2][0], 0, 0, 0);
        acc[2][0] = __builtin_amdgcn_mfma_f32_16x16x32_bf16(ch0, dl, acc[2][0], 0, 0, 0);
        acc[2][0] = __builtin_amdgcn_mfma_f32_16x16x32_bf16(cl0, dh, acc[2][0], 0, 0, 0);
        acc[2][1] = __builtin_amdgcn_mfma_f32_16x16x32_bf16(ch1, dh, acc[2][1], 0, 0, 0);
        acc[2][1] = __builtin_amdgcn_mfma_f32_16x16x32_bf16(ch1, dl, acc[2][1], 0, 0, 0);
        acc[2][1] = __builtin_amdgcn_mfma_f32_16x16x32_bf16(cl1, dh, acc[2][1], 0, 0, 0);
      }
    }

    // write C partials: col = fr, row(batch) = mf*16 + (lane>>4)*4 + j
    #pragma unroll
    for (int m = 0; m < 3; ++m)
      #pragma unroll
      for (int mf = 0; mf < 2; ++mf)
        #pragma unroll
        for (int j = 0; j < 4; ++j)
          gpart[(m * 4 + w) * 512 + fr * 32 + mf * 16 + (lane >> 4) * 4 + j] = acc[m][mf][j];
    __syncthreads();

    // ---- pointwise (tid<128: L0, tid>=128: L1) ----
    if (tid < 128) {
      if (doL0) {
        float g[4];
        #pragma unroll
        for (int gt = 0; gt < 4; ++gt) {
          int base = (gt * 4 + cl) * 32 + b2;
          float s = gx[base];
          #pragma unroll
          for (int ww = 0; ww < 4; ++ww) s += gpart[ww * 512 + base];
          g[gt] = s;
        }
        float i_ = 1.f / (1.f + expf(-g[0]));
        float f_ = 1.f / (1.f + expf(-g[1]));
        float gg = tanhf(g[2]);
        float o_ = 1.f / (1.f + expf(-g[3]));
        float cn = f_ * creg + i_ * gg;
        float hn = o_ * tanhf(cn);
        creg = cn;
        unsigned int uu = __float_as_uint(hn);
        unsigned int hr = (uu + 0x7fffu + ((uu >> 16) & 1u)) & 0xffff0000u;
        float rem = hn - __uint_as_float(hr);
        unsigned int u2 = __float_as_uint(rem);
        hstage[(0 * 32 + b2) * 4 + cl] = (unsigned short)(hr >> 16);
        hstage[(1 * 32 + b2) * 4 + cl] =
            (unsigned short)((u2 + 0x7fffu + ((u2 >> 16) & 1u)) >> 16);
      }
    } else {
      if (doL1) {
        float g[4];
        #pragma unroll
        for (int gt = 0; gt < 4; ++gt) {
          int base = (gt * 4 + cl) * 32 + b2;
          float s = 0.f;
          #pragma unroll
          for (int ww = 0; ww < 4; ++ww)
            s += gpart[(4 + ww) * 512 + base] + gpart[(8 + ww) * 512 + base];
          g[gt] = s;
        }
        g[0] += bv0; g[1] += bv1; g[2] += bv2; g[3] += bv3;
        float i_ = 1.f / (1.f + expf(-g[0]));
        float f_ = 1.f / (1.f + expf(-g[1]));
        float gg = tanhf(g[2]);
        float o_ = 1.f / (1.f + expf(-g[3]));
        float cn = f_ * creg + i_ * gg;
        float hn = o_ * tanhf(cn);
        creg = cn;
        unsigned int uu = __float_as_uint(hn);
        unsigned int hr = (uu + 0x7fffu + ((uu >> 16) & 1u)) & 0xffff0000u;
        float rem = hn - __uint_as_float(hr);
        unsigned int u2 = __float_as_uint(rem);
        hstage[(2 * 32 + b2) * 4 + cl] = (unsigned short)(hr >> 16);
        hstage[(3 * 32 + b2) * 4 + cl] =
            (unsigned short)((u2 + 0x7fffu + ((u2 >> 16) & 1u)) >> 16);
      }
    }
    __syncthreads();

    // packed 8B write-through h stores (4 cells contiguous)
    if (tid < 128) {
      int layer = tid >> 6, hl = (tid >> 5) & 1, bb = tid & 31;
      bool go = layer ? doL1 : doL0;
      if (go) {
        unsigned long long v =
            *(const unsigned long long*)&hstage[((layer * 2 + hl) * 32 + bb) * 4];
        unsigned short* arr = layer ? (hl ? h1lo : h1hi) : (hl ? h0lo : h0hi);
        int slot = layer ? (u - 1) : u;
        __hip_atomic_store((unsigned long long*)&arr[(size_t)slot * SLOT + bb * 512 + blk * 4],
                           v, __ATOMIC_RELAXED, __HIP_MEMORY_SCOPE_AGENT);
      }
    }
    asm volatile("s_waitcnt vmcnt(0)" ::: "memory");
    __syncthreads();
    if (tid == 0)
      __hip_atomic_store(&flag[blk * BARSTRIDE], u + 1,
                         __ATOMIC_RELAXED, __HIP_MEMORY_SCOPE_AGENT);
  }

  // final c handoff
  if (tid < 128) c0fin[b2 * 512 + nn] = creg;
  else           c1fin[b2 * 512 + nn] = creg;
}

// ---------------- host ----------------
extern "C" void kernel_launch(void* const* d_in, const int* in_sizes, int n_in,
                              void* d_out, int out_size, void* d_ws, size_t ws_size,
                              hipStream_t stream) {
  const int*   src  = (const int*)d_in[0];
  const int*   tgt  = (const int*)d_in[1];
  const float* emb  = (const float*)d_in[2];
  const float* Wout = (const float*)d_in[3];
  const float* bout = (const float*)d_in[4];
  const float* eWih0 = (const float*)d_in[5];
  const float* eWhh0 = (const float*)d_in[6];
  const float* ebih0 = (const float*)d_in[7];
  const float* ebhh0 = (const float*)d_in[8];
  const float* eWih1 = (const float*)d_in[9];
  const float* eWhh1 = (const float*)d_in[10];
  const float* ebih1 = (const float*)d_in[11];
  const float* ebhh1 = (const float*)d_in[12];
  const float* dWih0 = (const float*)d_in[13];
  const float* dWhh0 = (const float*)d_in[14];
  const float* dbih0 = (const float*)d_in[15];
  const float* dbhh0 = (const float*)d_in[16];
  const float* dWih1 = (const float*)d_in[17];
  const float* dWhh1 = (const float*)d_in[18];
  const float* dbih1 = (const float*)d_in[19];
  const float* dbhh1 = (const float*)d_in[20];

  if (ws_size < 86245376ull) return;   // layout requirement (harness provides >= 96 MB)

  float* ws = (float*)d_ws;
  char*  wsb = (char*)d_ws;
  // layout (bytes):
  // 0         : EMB fp32 4096x256           (4 MB)   [dead at projection]
  // 4194304   : X0 fp32 4096x2048           (32 MB)  [dead at projection]
  // 37748736  : 6 weight packs x 4 MB       (24 MB)  [dead at projection]
  // 62914560  : bias sums 4 x 2048 f32
  // 62947328  : zeros 64 KB + flags 32 KB
  // 63045632  : c0fin/c1fin 2 x 64 KB
  // 63176704  : Ehi/Elo/WIhi/WIlo           (6 MB)   [dead at projection]
  // 69468160  : h0hi/h0lo/h1hi/h1lo 4x4 MB  (16 MB)  [LIVE at projection]
  // projection overlays: Bhi@0, Blo@32768000 (end 65.5 MB < 69.4 MB) OK
  unsigned short* PK   = (unsigned short*)(wsb + 37748736);
  unsigned short* PW0E = PK;
  unsigned short* PW1AE = PK + 2097152;
  unsigned short* PW1BE = PK + 4194304;
  unsigned short* PW0D = PK + 6291456;
  unsigned short* PW1AD = PK + 8388608;
  unsigned short* PW1BD = PK + 10485760;
  const size_t OFF_EMB  = 0;
  const size_t OFF_X0   = 1048576;      // floats
  const size_t OFF_BS0E = 15728640;
  const size_t OFF_B1E  = 15730688;
  const size_t OFF_BS0D = 15732736;
  const size_t OFF_B1D  = 15734784;
  const size_t OFF_Z    = 15736832;     // 16384 f zeros
  const size_t OFF_BAR  = 15753216;     // 8192 ints
  const size_t OFF_C0   = 15761408;
  const size_t OFF_C1   = 15777792;
  unsigned short* Ehi  = (unsigned short*)(wsb + 63176704);
  unsigned short* Elo  = (unsigned short*)(wsb + 65273856);
  unsigned short* WIhi = (unsigned short*)(wsb + 67371008);
  unsigned short* WIlo = (unsigned short*)(wsb + 68419584);
  unsigned short* H0hi = (unsigned short*)(wsb + 69468160);
  unsigned short* H0lo = (unsigned short*)(wsb + 73662464);
  unsigned short* H1hi = (unsigned short*)(wsb + 77856768);
  unsigned short* H1lo = (unsigned short*)(wsb + 82051072);
  unsigned short* Bhi  = (unsigned short*)(wsb + 0);
  unsigned short* Blo  = (unsigned short*)(wsb + 32768000);
  const unsigned short* ZU = (const unsigned short*)(ws + OFF_Z);
  const float* ZF = ws + OFF_Z;

  int* eflag = (int*)(ws + OFF_BAR);
  int* dflag = eflag + 4096;

  // packs + bias sums
  pack_wbf_k<<<128, 256, 0, stream>>>(eWhh0, PW0E);
  pack_wbf_k<<<128, 256, 0, stream>>>(eWih1, PW1AE);
  pack_wbf_k<<<128, 256, 0, stream>>>(eWhh1, PW1BE);
  pack_wbf_k<<<128, 256, 0, stream>>>(dWhh0, PW0D);
  pack_wbf_k<<<128, 256, 0, stream>>>(dWih1, PW1AD);
  pack_wbf_k<<<128, 256, 0, stream>>>(dWhh1, PW1BD);
  bias_sum_k<<<8, 256, 0, stream>>>(ebih0, ebhh0, ws + OFF_BS0E);
  bias_sum_k<<<8, 256, 0, stream>>>(ebih1, ebhh1, ws + OFF_B1E);
  bias_sum_k<<<8, 256, 0, stream>>>(dbih0, dbhh0, ws + OFF_BS0D);
  bias_sum_k<<<8, 256, 0, stream>>>(dbih1, dbhh1, ws + OFF_B1D);

  // zero zeros+flags (contiguous 96 KB) each call
  hipMemsetAsync(ws + OFF_Z, 0, 98304, stream);

  // ---- encoder ----
  embed_k<<<1024, 256, 0, stream>>>(src, emb, ws + OFF_EMB);
  split_k<<<1024, 256, 0, stream>>>(ws + OFF_EMB, Ehi, Elo);
  split_k<<<512, 256, 0, stream>>>(eWih0, WIhi, WIlo);
  gemm_bfs_k<<<dim3(32, 16), 256, 0, stream>>>(Ehi, Elo, WIhi, WIlo,
                                               ws + OFF_BS0E, ws + OFF_X0, 256, 2048, 0);
  lstm_seq_k<<<128, 256, 0, stream>>>(PW0E, PW1AE, PW1BE,
                                      ws + OFF_X0, ws + OFF_B1E,
                                      H0hi, H0lo, H1hi, H1lo,
                                      ZU, ZU, ZU, ZU,            // h inits (zeros)
                                      ZF, ZF,                    // c inits (zeros)
                                      ws + OFF_C0, ws + OFF_C1,  // c finals
                                      eflag);

  // ---- decoder (inits = encoder finals, slot 127) ----
  embed_k<<<1024, 256, 0, stream>>>(tgt, emb, ws + OFF_EMB);
  split_k<<<1024, 256, 0, stream>>>(ws + OFF_EMB, Ehi, Elo);
  split_k<<<512, 256, 0, stream>>>(dWih0, WIhi, WIlo);
  gemm_bfs_k<<<dim3(32, 16), 256, 0, stream>>>(Ehi, Elo, WIhi, WIlo,
                                               ws + OFF_BS0D, ws + OFF_X0, 256, 2048, 0);
  lstm_seq_k<<<128, 256, 0, stream>>>(PW0D, PW1AD, PW1BD,
                                      ws + OFF_X0, ws + OFF_B1D,
                                      H0hi, H0lo, H1hi, H1lo,
                                      H0hi + (size_t)127 * SLOT, H0lo + (size_t)127 * SLOT,
                                      H1hi + (size_t)127 * SLOT, H1lo + (size_t)127 * SLOT,
                                      ws + OFF_C0, ws + OFF_C1,
                                      ws + OFF_C0, ws + OFF_C1,
                                      dflag);

  // ---- vocab projection: A = dec h1 slots (bf16 hi/lo, amode=1 row remap) ----
  split_k<<<16000, 256, 0, stream>>>(Wout, Bhi, Blo);
  gemm_bfs_k<<<dim3(32, 250), 256, 0, stream>>>(H1hi, H1lo, Bhi, Blo,
                                                bout, (float*)d_out, 512, 32000, 1);
}

// Round 14
// 2219.731 us; speedup vs baseline: 1.9604x; 1.0670x over previous
//
#include <hip/hip_runtime.h>
#include <math.h>

#define Bsz 32
#define Hd  512
#define SEQ 128
#define G4H 2048
#define BH  16384
#define BARSTRIDE 32
#define SLOT 16384   // 32*512 ushorts per h step-slot

typedef __attribute__((ext_vector_type(8))) short bf16x8;
typedef __attribute__((ext_vector_type(4))) float f32x4;
typedef __attribute__((ext_vector_type(4))) unsigned short us4;

__device__ __forceinline__ void gload16(const void* g, void* l) {
  __builtin_amdgcn_global_load_lds(
      (const __attribute__((address_space(1))) unsigned int*)g,
      (__attribute__((address_space(3))) unsigned int*)l, 16, 0, 0);
}

__global__ __launch_bounds__(256) void bias_sum_k(const float* __restrict__ a,
                                                  const float* __restrict__ b,
                                                  float* __restrict__ out) {
  int i = blockIdx.x * 256 + threadIdx.x;
  if (i < G4H) out[i] = a[i] + b[i];
}

__global__ __launch_bounds__(256) void embed_k(const int* __restrict__ idx,
                                               const float* __restrict__ emb,
                                               float* __restrict__ out) {
  int t = blockIdx.x * 256 + threadIdx.x;
  int m = t >> 6, e4 = (t & 63) << 2;
  *(float4*)&out[(size_t)m * 256 + e4] =
      *(const float4*)&emb[(size_t)idx[m] * 256 + e4];
}

// ---------------- fp32 -> bf16 hi/lo split ----------------
__global__ __launch_bounds__(256) void split_k(const float* __restrict__ X,
                                               unsigned short* __restrict__ hi,
                                               unsigned short* __restrict__ lo) {
  int i = (blockIdx.x * 256 + threadIdx.x) << 2;
  float4 x = *(const float4*)&X[i];
  const float* xp = (const float*)&x;
  us4 h, l;
  #pragma unroll
  for (int e = 0; e < 4; ++e) {
    float v = xp[e];
    unsigned int u = __float_as_uint(v);
    unsigned int hr = (u + 0x7fffu + ((u >> 16) & 1u)) & 0xffff0000u;
    h[e] = (unsigned short)(hr >> 16);
    float rem = v - __uint_as_float(hr);
    unsigned int u2 = __float_as_uint(rem);
    l[e] = (unsigned short)((u2 + 0x7fffu + ((u2 >> 16) & 1u)) >> 16);
  }
  *(us4*)&hi[i] = h;
  *(us4*)&lo[i] = l;
}

// ---------------- weight pack: bf16 hi/lo in MFMA B-fragment layout ----------------
__global__ __launch_bounds__(256) void pack_wbf_k(const float* __restrict__ W,
                                                  unsigned short* __restrict__ out) {
  __shared__ float Wl[16][512];
  const int blk = blockIdx.x, tid = threadIdx.x;
  #pragma unroll
  for (int r = 0; r < 16; ++r) {
    int j = (r >> 2) * 512 + blk * 4 + (r & 3);
    Wl[r][tid]       = W[(size_t)j * 512 + tid];
    Wl[r][tid + 256] = W[(size_t)j * 512 + tid + 256];
  }
  __syncthreads();
  for (int idx = tid; idx < 8192; idx += 256) {
    int kf = idx >> 9, l = (idx >> 3) & 63, e = idx & 7;
    int col = l & 15;
    int kpos = (kf << 5) + ((l >> 4) << 3) + e;
    float v = Wl[col][kpos];
    unsigned int uu = __float_as_uint(v);
    unsigned int hr = (uu + 0x7fffu + ((uu >> 16) & 1u)) & 0xffff0000u;
    float rem = v - __uint_as_float(hr);
    unsigned int u2 = __float_as_uint(rem);
    out[(size_t)blk * 16384 + idx] = (unsigned short)(hr >> 16);
    out[(size_t)blk * 16384 + 8192 + idx] =
        (unsigned short)((u2 + 0x7fffu + ((u2 >> 16) & 1u)) >> 16);
  }
}

// ---------------- bf16 MFMA 3-term split GEMM, MERGED single K-pass ----------------
// C = Ahi.Bhi + Ahi.Blo + Alo.Bhi (+bias); 48 MFMA per kt, 2 barriers per kt.
__global__ __launch_bounds__(256)
void gemm_bfs_k(const unsigned short* __restrict__ Ahi,
                const unsigned short* __restrict__ Alo,
                const unsigned short* __restrict__ Bhi,
                const unsigned short* __restrict__ Blo,
                const float* __restrict__ bias,
                float* __restrict__ C, int K, int ldc, int amode)
{
  __shared__ unsigned short Ash[4096], Asl[4096];
  __shared__ unsigned short Bsh[4096], Bsl[4096];
  const int tid = threadIdx.x;
  const int m0 = blockIdx.x << 7, n0 = blockIdx.y << 7;
  const int lane = tid & 63, wave = tid >> 6;
  const int wr = wave >> 1, wc = wave & 1;
  const int srow = wave * 32 + (lane >> 2);
  const int sk = (lane & 3) << 3;
  const int ldse = wave * 1024 + lane * 8;
  const int fr = lane & 15, fk = (lane >> 4) << 3;

  const int r1 = m0 + srow, r2 = m0 + srow + 16;
  const size_t ra1 = amode ? ((size_t)(r1 & 127) * 32 + (r1 >> 7)) * 512 : (size_t)r1 * K;
  const size_t ra2 = amode ? ((size_t)(r2 & 127) * 32 + (r2 >> 7)) * 512 : (size_t)r2 * K;
  const size_t rb1 = (size_t)(n0 + srow) * K, rb2 = (size_t)(n0 + srow + 16) * K;

  f32x4 acc[4][4];
  #pragma unroll
  for (int a = 0; a < 4; ++a)
    #pragma unroll
    for (int b = 0; b < 4; ++b) acc[a][b] = (f32x4){0.f, 0.f, 0.f, 0.f};

  #pragma unroll 1
  for (int kt = 0; kt < K; kt += 32) {
    gload16(Ahi + ra1 + kt + sk, &Ash[ldse]);
    gload16(Ahi + ra2 + kt + sk, &Ash[ldse + 512]);
    gload16(Alo + ra1 + kt + sk, &Asl[ldse]);
    gload16(Alo + ra2 + kt + sk, &Asl[ldse + 512]);
    gload16(Bhi + rb1 + kt + sk, &Bsh[ldse]);
    gload16(Bhi + rb2 + kt + sk, &Bsh[ldse + 512]);
    gload16(Blo + rb1 + kt + sk, &Bsl[ldse]);
    gload16(Blo + rb2 + kt + sk, &Bsl[ldse + 512]);
    __syncthreads();
    bf16x8 afh[4], afl[4], bfh[4], bfl[4];
    #pragma unroll
    for (int mf = 0; mf < 4; ++mf) {
      afh[mf] = *(const bf16x8*)&Ash[(wr * 64 + mf * 16 + fr) * 32 + fk];
      afl[mf] = *(const bf16x8*)&Asl[(wr * 64 + mf * 16 + fr) * 32 + fk];
    }
    #pragma unroll
    for (int nf = 0; nf < 4; ++nf) {
      bfh[nf] = *(const bf16x8*)&Bsh[(wc * 64 + nf * 16 + fr) * 32 + fk];
      bfl[nf] = *(const bf16x8*)&Bsl[(wc * 64 + nf * 16 + fr) * 32 + fk];
    }
    #pragma unroll
    for (int mf = 0; mf < 4; ++mf)
      #pragma unroll
      for (int nf = 0; nf < 4; ++nf) {
        acc[mf][nf] = __builtin_amdgcn_mfma_f32_16x16x32_bf16(afh[mf], bfh[nf],
                                                              acc[mf][nf], 0, 0, 0);
        acc[mf][nf] = __builtin_amdgcn_mfma_f32_16x16x32_bf16(afh[mf], bfl[nf],
                                                              acc[mf][nf], 0, 0, 0);
        acc[mf][nf] = __builtin_amdgcn_mfma_f32_16x16x32_bf16(afl[mf], bfh[nf],
                                                              acc[mf][nf], 0, 0, 0);
      }
    __syncthreads();
  }

  const int rgrp = (lane >> 4) << 2;
  #pragma unroll
  for (int nf = 0; nf < 4; ++nf) {
    int n = n0 + wc * 64 + nf * 16 + fr;
    float bn = bias[n];
    #pragma unroll
    for (int mf = 0; mf < 4; ++mf) {
      #pragma unroll
      for (int r = 0; r < 4; ++r) {
        int m = m0 + wr * 64 + mf * 16 + rgrp + r;
        C[(size_t)m * ldc + n] = acc[mf][nf][r] + bn;
      }
    }
  }
}

// ---------------- spread-flag sync (128 blocks, 1 cacheline each) ----------------
__device__ __forceinline__ void pollwait(const int* arr, int target) {
  const int tid = threadIdx.x;
  if (tid < 64) {
    const int* p0 = &arr[tid * BARSTRIDE];
    const int* p1 = &arr[(tid + 64) * BARSTRIDE];
    for (;;) {
      int a = __hip_atomic_load(p0, __ATOMIC_RELAXED, __HIP_MEMORY_SCOPE_AGENT);
      int b = __hip_atomic_load(p1, __ATOMIC_RELAXED, __HIP_MEMORY_SCOPE_AGENT);
      if (__all(min(a, b) >= target)) break;
      __builtin_amdgcn_s_sleep(1);
    }
  }
  __syncthreads();
}

// ---------------- persistent LSTM: MFMA recurrence, conflict-fixed gpart ----------------
// gpart layout [mat4w 12][row 32][col pad-17]: write 4-way max, read ~2-way.
__global__ __launch_bounds__(256, 1)
void lstm_seq_k(const unsigned short* __restrict__ pw0,
                const unsigned short* __restrict__ pw1a,
                const unsigned short* __restrict__ pw1b,
                const float* __restrict__ x0pre,
                const float* __restrict__ bias1,
                unsigned short* __restrict__ h0hi, unsigned short* __restrict__ h0lo,
                unsigned short* __restrict__ h1hi, unsigned short* __restrict__ h1lo,
                const unsigned short* __restrict__ h0ihi, const unsigned short* __restrict__ h0ilo,
                const unsigned short* __restrict__ h1ihi, const unsigned short* __restrict__ h1ilo,
                const float* __restrict__ c0init, const float* __restrict__ c1init,
                float* __restrict__ c0fin, float* __restrict__ c1fin,
                int* __restrict__ flag)
{
  __shared__ unsigned short wlds[49152];  // 3 mats x [half2][kf16][lane64][e8]
  __shared__ float gpart[6528];           // [12][32][17]
  __shared__ float gx[512];               // [col16][b32]
  __shared__ unsigned short hstage[512];  // [layer2][hl2][b32][cl4]

  const int blk = blockIdx.x, tid = threadIdx.x;
  const int w = tid >> 6, lane = tid & 63;
  const int fr = lane & 15, fgk = (lane >> 4) << 3;

  // stage 3 packed weight mats (32 KB each)
  {
    const uint4* s0 = (const uint4*)(pw0 + (size_t)blk * 16384);
    const uint4* s1 = (const uint4*)(pw1a + (size_t)blk * 16384);
    const uint4* s2 = (const uint4*)(pw1b + (size_t)blk * 16384);
    uint4* d = (uint4*)wlds;
    for (int i = tid; i < 2048; i += 256) {
      d[i] = s0[i]; d[2048 + i] = s1[i]; d[4096 + i] = s2[i];
    }
  }

  const int cl = (tid >> 5) & 3, b2 = tid & 31;
  const int nn = blk * 4 + cl;
  float creg, bv0 = 0.f, bv1 = 0.f, bv2 = 0.f, bv3 = 0.f;
  if (tid < 128) {
    creg = c0init[b2 * 512 + nn];
  } else {
    creg = c1init[b2 * 512 + nn];
    bv0 = bias1[nn]; bv1 = bias1[512 + nn];
    bv2 = bias1[1024 + nn]; bv3 = bias1[1536 + nn];
  }
  const int xcol = tid & 15, xb = tid >> 4;
  const int xj = (xcol >> 2) * 512 + blk * 4 + (xcol & 3);
  __syncthreads();

  #pragma unroll 1
  for (int u = 0; u <= SEQ; ++u) {
    const bool doL0 = (u < SEQ), doL1 = (u >= 1);

    float xv0 = 0.f, xv1 = 0.f;
    if (doL0) {
      xv0 = x0pre[((size_t)xb * SEQ + u) * G4H + xj];
      xv1 = x0pre[((size_t)(xb + 16) * SEQ + u) * G4H + xj];
    }

    if (u > 0) pollwait(flag, u);

    if (doL0) { gx[xcol * 32 + xb] = xv0; gx[xcol * 32 + xb + 16] = xv1; }

    const unsigned short* hAh = (u == 0) ? h0ihi : h0hi + (size_t)(u - 1) * SLOT;
    const unsigned short* hAl = (u == 0) ? h0ilo : h0lo + (size_t)(u - 1) * SLOT;
    const unsigned short* hBh = (u <= 1) ? h1ihi : h1hi + (size_t)(u - 2) * SLOT;
    const unsigned short* hBl = (u <= 1) ? h1ilo : h1lo + (size_t)(u - 2) * SLOT;

    f32x4 acc[3][2];
    #pragma unroll
    for (int m = 0; m < 3; ++m) {
      acc[m][0] = (f32x4){0.f, 0.f, 0.f, 0.f};
      acc[m][1] = (f32x4){0.f, 0.f, 0.f, 0.f};
    }

    #pragma unroll
    for (int q = 0; q < 4; ++q) {
      const int kf = (w << 2) + q;
      const int ko = (kf << 5) + fgk;
      const int wko = (kf << 9) + lane * 8;
      bf16x8 ah0 = *(const bf16x8*)&hAh[(size_t)fr * 512 + ko];
      bf16x8 al0 = *(const bf16x8*)&hAl[(size_t)fr * 512 + ko];
      bf16x8 ah1 = *(const bf16x8*)&hAh[(size_t)(fr + 16) * 512 + ko];
      bf16x8 al1 = *(const bf16x8*)&hAl[(size_t)(fr + 16) * 512 + ko];
      if (doL0) {
        bf16x8 bh = *(const bf16x8*)&wlds[wko];
        bf16x8 bl = *(const bf16x8*)&wlds[8192 + wko];
        acc[0][0] = __builtin_amdgcn_mfma_f32_16x16x32_bf16(ah0, bh, acc[0][0], 0, 0, 0);
        acc[0][0] = __builtin_amdgcn_mfma_f32_16x16x32_bf16(ah0, bl, acc[0][0], 0, 0, 0);
        acc[0][0] = __builtin_amdgcn_mfma_f32_16x16x32_bf16(al0, bh, acc[0][0], 0, 0, 0);
        acc[0][1] = __builtin_amdgcn_mfma_f32_16x16x32_bf16(ah1, bh, acc[0][1], 0, 0, 0);
        acc[0][1] = __builtin_amdgcn_mfma_f32_16x16x32_bf16(ah1, bl, acc[0][1], 0, 0, 0);
        acc[0][1] = __builtin_amdgcn_mfma_f32_16x16x32_bf16(al1, bh, acc[0][1], 0, 0, 0);
      }
      if (doL1) {
        bf16x8 bh = *(const bf16x8*)&wlds[16384 + wko];
        bf16x8 bl = *(const bf16x8*)&wlds[16384 + 8192 + wko];
        acc[1][0] = __builtin_amdgcn_mfma_f32_16x16x32_bf16(ah0, bh, acc[1][0], 0, 0, 0);
        acc[1][0] = __builtin_amdgcn_mfma_f32_16x16x32_bf16(ah0, bl, acc[1][0], 0, 0, 0);
        acc[1][0] = __builtin_amdgcn_mfma_f32_16x16x32_bf16(al0, bh, acc[1][0], 0, 0, 0);
        acc[1][1] = __builtin_amdgcn_mfma_f32_16x16x32_bf16(ah1, bh, acc[1][1], 0, 0, 0);
        acc[1][1] = __builtin_amdgcn_mfma_f32_16x16x32_bf16(ah1, bl, acc[1][1], 0, 0, 0);
        acc[1][1] = __builtin_amdgcn_mfma_f32_16x16x32_bf16(al1, bh, acc[1][1], 0, 0, 0);
        bf16x8 ch0 = *(const bf16x8*)&hBh[(size_t)fr * 512 + ko];
        bf16x8 cl0 = *(const bf16x8*)&hBl[(size_t)fr * 512 + ko];
        bf16x8 ch1 = *(const bf16x8*)&hBh[(size_t)(fr + 16) * 512 + ko];
        bf16x8 cl1 = *(const bf16x8*)&hBl[(size_t)(fr + 16) * 512 + ko];
        bf16x8 dh = *(const bf16x8*)&wlds[32768 + wko];
        bf16x8 dl = *(const bf16x8*)&wlds[32768 + 8192 + wko];
        acc[2][0] = __builtin_amdgcn_mfma_f32_16x16x32_bf16(ch0, dh, acc[2][0], 0, 0, 0);
        acc[2][0] = __builtin_amdgcn_mfma_f32_16x16x32_bf16(ch0, dl, acc[2][0], 0, 0, 0);
        acc[2][0] = __builtin_amdgcn_mfma_f32_16x16x32_bf16(cl0, dh, acc[2][0], 0, 0, 0);
        acc[2][1] = __builtin_amdgcn_mfma_f32_16x16x32_bf16(ch1, dh, acc[2][1], 0, 0, 0);
        acc[2][1] = __builtin_amdgcn_mfma_f32_16x16x32_bf16(ch1, dl, acc[2][1], 0, 0, 0);
        acc[2][1] = __builtin_amdgcn_mfma_f32_16x16x32_bf16(cl1, dh, acc[2][1], 0, 0, 0);
      }
    }

    // write C partials: [mat4w][row = mf*16+(lane>>4)*4+j][col fr], col stride 17
    #pragma unroll
    for (int m = 0; m < 3; ++m)
      #pragma unroll
      for (int mf = 0; mf < 2; ++mf)
        #pragma unroll
        for (int j = 0; j < 4; ++j)
          gpart[(m * 4 + w) * 544 + (mf * 16 + (lane >> 4) * 4 + j) * 17 + fr] = acc[m][mf][j];
    __syncthreads();

    // ---- pointwise (tid<128: L0, tid>=128: L1) ----
    if (tid < 128) {
      if (doL0) {
        float g[4];
        #pragma unroll
        for (int gt = 0; gt < 4; ++gt) {
          float s = gx[(gt * 4 + cl) * 32 + b2];
          #pragma unroll
          for (int ww = 0; ww < 4; ++ww)
            s += gpart[ww * 544 + b2 * 17 + gt * 4 + cl];
          g[gt] = s;
        }
        float i_ = 1.f / (1.f + expf(-g[0]));
        float f_ = 1.f / (1.f + expf(-g[1]));
        float gg = tanhf(g[2]);
        float o_ = 1.f / (1.f + expf(-g[3]));
        float cn = f_ * creg + i_ * gg;
        float hn = o_ * tanhf(cn);
        creg = cn;
        unsigned int uu = __float_as_uint(hn);
        unsigned int hr = (uu + 0x7fffu + ((uu >> 16) & 1u)) & 0xffff0000u;
        float rem = hn - __uint_as_float(hr);
        unsigned int u2 = __float_as_uint(rem);
        hstage[(0 * 32 + b2) * 4 + cl] = (unsigned short)(hr >> 16);
        hstage[(1 * 32 + b2) * 4 + cl] =
            (unsigned short)((u2 + 0x7fffu + ((u2 >> 16) & 1u)) >> 16);
      }
    } else {
      if (doL1) {
        float g[4];
        #pragma unroll
        for (int gt = 0; gt < 4; ++gt) {
          float s = 0.f;
          #pragma unroll
          for (int ww = 0; ww < 4; ++ww)
            s += gpart[(4 + ww) * 544 + b2 * 17 + gt * 4 + cl]
               + gpart[(8 + ww) * 544 + b2 * 17 + gt * 4 + cl];
          g[gt] = s;
        }
        g[0] += bv0; g[1] += bv1; g[2] += bv2; g[3] += bv3;
        float i_ = 1.f / (1.f + expf(-g[0]));
        float f_ = 1.f / (1.f + expf(-g[1]));
        float gg = tanhf(g[2]);
        float o_ = 1.f / (1.f + expf(-g[3]));
        float cn = f_ * creg + i_ * gg;
        float hn = o_ * tanhf(cn);
        creg = cn;
        unsigned int uu = __float_as_uint(hn);
        unsigned int hr = (uu + 0x7fffu + ((uu >> 16) & 1u)) & 0xffff0000u;
        float rem = hn - __uint_as_float(hr);
        unsigned int u2 = __float_as_uint(rem);
        hstage[(2 * 32 + b2) * 4 + cl] = (unsigned short)(hr >> 16);
        hstage[(3 * 32 + b2) * 4 + cl] =
            (unsigned short)((u2 + 0x7fffu + ((u2 >> 16) & 1u)) >> 16);
      }
    }
    __syncthreads();

    // packed 8B write-through h stores (4 cells contiguous)
    if (tid < 128) {
      int layer = tid >> 6, hl = (tid >> 5) & 1, bb = tid & 31;
      bool go = layer ? doL1 : doL0;
      if (go) {
        unsigned long long v =
            *(const unsigned long long*)&hstage[((layer * 2 + hl) * 32 + bb) * 4];
        unsigned short* arr = layer ? (hl ? h1lo : h1hi) : (hl ? h0lo : h0hi);
        int slot = layer ? (u - 1) : u;
        __hip_atomic_store((unsigned long long*)&arr[(size_t)slot * SLOT + bb * 512 + blk * 4],
                           v, __ATOMIC_RELAXED, __HIP_MEMORY_SCOPE_AGENT);
      }
    }
    asm volatile("s_waitcnt vmcnt(0)" ::: "memory");
    __syncthreads();
    if (tid == 0)
      __hip_atomic_store(&flag[blk * BARSTRIDE], u + 1,
                         __ATOMIC_RELAXED, __HIP_MEMORY_SCOPE_AGENT);
  }

  if (tid < 128) c0fin[b2 * 512 + nn] = creg;
  else           c1fin[b2 * 512 + nn] = creg;
}

// ---------------- host ----------------
extern "C" void kernel_launch(void* const* d_in, const int* in_sizes, int n_in,
                              void* d_out, int out_size, void* d_ws, size_t ws_size,
                              hipStream_t stream) {
  const int*   src  = (const int*)d_in[0];
  const int*   tgt  = (const int*)d_in[1];
  const float* emb  = (const float*)d_in[2];
  const float* Wout = (const float*)d_in[3];
  const float* bout = (const float*)d_in[4];
  const float* eWih0 = (const float*)d_in[5];
  const float* eWhh0 = (const float*)d_in[6];
  const float* ebih0 = (const float*)d_in[7];
  const float* ebhh0 = (const float*)d_in[8];
  const float* eWih1 = (const float*)d_in[9];
  const float* eWhh1 = (const float*)d_in[10];
  const float* ebih1 = (const float*)d_in[11];
  const float* ebhh1 = (const float*)d_in[12];
  const float* dWih0 = (const float*)d_in[13];
  const float* dWhh0 = (const float*)d_in[14];
  const float* dbih0 = (const float*)d_in[15];
  const float* dbhh0 = (const float*)d_in[16];
  const float* dWih1 = (const float*)d_in[17];
  const float* dWhh1 = (const float*)d_in[18];
  const float* dbih1 = (const float*)d_in[19];
  const float* dbhh1 = (const float*)d_in[20];

  if (ws_size < 86245376ull) return;

  float* ws = (float*)d_ws;
  char*  wsb = (char*)d_ws;
  unsigned short* PK   = (unsigned short*)(wsb + 37748736);
  unsigned short* PW0E = PK;
  unsigned short* PW1AE = PK + 2097152;
  unsigned short* PW1BE = PK + 4194304;
  unsigned short* PW0D = PK + 6291456;
  unsigned short* PW1AD = PK + 8388608;
  unsigned short* PW1BD = PK + 10485760;
  const size_t OFF_EMB  = 0;
  const size_t OFF_X0   = 1048576;
  const size_t OFF_BS0E = 15728640;
  const size_t OFF_B1E  = 15730688;
  const size_t OFF_BS0D = 15732736;
  const size_t OFF_B1D  = 15734784;
  const size_t OFF_Z    = 15736832;
  const size_t OFF_BAR  = 15753216;
  const size_t OFF_C0   = 15761408;
  const size_t OFF_C1   = 15777792;
  unsigned short* Ehi  = (unsigned short*)(wsb + 63176704);
  unsigned short* Elo  = (unsigned short*)(wsb + 65273856);
  unsigned short* WIhi = (unsigned short*)(wsb + 67371008);
  unsigned short* WIlo = (unsigned short*)(wsb + 68419584);
  unsigned short* H0hi = (unsigned short*)(wsb + 69468160);
  unsigned short* H0lo = (unsigned short*)(wsb + 73662464);
  unsigned short* H1hi = (unsigned short*)(wsb + 77856768);
  unsigned short* H1lo = (unsigned short*)(wsb + 82051072);
  unsigned short* Bhi  = (unsigned short*)(wsb + 0);
  unsigned short* Blo  = (unsigned short*)(wsb + 32768000);
  const unsigned short* ZU = (const unsigned short*)(ws + OFF_Z);
  const float* ZF = ws + OFF_Z;

  int* eflag = (int*)(ws + OFF_BAR);
  int* dflag = eflag + 4096;

  pack_wbf_k<<<128, 256, 0, stream>>>(eWhh0, PW0E);
  pack_wbf_k<<<128, 256, 0, stream>>>(eWih1, PW1AE);
  pack_wbf_k<<<128, 256, 0, stream>>>(eWhh1, PW1BE);
  pack_wbf_k<<<128, 256, 0, stream>>>(dWhh0, PW0D);
  pack_wbf_k<<<128, 256, 0, stream>>>(dWih1, PW1AD);
  pack_wbf_k<<<128, 256, 0, stream>>>(dWhh1, PW1BD);
  bias_sum_k<<<8, 256, 0, stream>>>(ebih0, ebhh0, ws + OFF_BS0E);
  bias_sum_k<<<8, 256, 0, stream>>>(ebih1, ebhh1, ws + OFF_B1E);
  bias_sum_k<<<8, 256, 0, stream>>>(dbih0, dbhh0, ws + OFF_BS0D);
  bias_sum_k<<<8, 256, 0, stream>>>(dbih1, dbhh1, ws + OFF_B1D);

  hipMemsetAsync(ws + OFF_Z, 0, 98304, stream);

  // ---- encoder ----
  embed_k<<<1024, 256, 0, stream>>>(src, emb, ws + OFF_EMB);
  split_k<<<1024, 256, 0, stream>>>(ws + OFF_EMB, Ehi, Elo);
  split_k<<<512, 256, 0, stream>>>(eWih0, WIhi, WIlo);
  gemm_bfs_k<<<dim3(32, 16), 256, 0, stream>>>(Ehi, Elo, WIhi, WIlo,
                                               ws + OFF_BS0E, ws + OFF_X0, 256, 2048, 0);
  lstm_seq_k<<<128, 256, 0, stream>>>(PW0E, PW1AE, PW1BE,
                                      ws + OFF_X0, ws + OFF_B1E,
                                      H0hi, H0lo, H1hi, H1lo,
                                      ZU, ZU, ZU, ZU,
                                      ZF, ZF,
                                      ws + OFF_C0, ws + OFF_C1,
                                      eflag);

  // ---- decoder (inits = encoder finals, slot 127) ----
  embed_k<<<1024, 256, 0, stream>>>(tgt, emb, ws + OFF_EMB);
  split_k<<<1024, 256, 0, stream>>>(ws + OFF_EMB, Ehi, Elo);
  split_k<<<512, 256, 0, stream>>>(dWih0, WIhi, WIlo);
  gemm_bfs_k<<<dim3(32, 16), 256, 0, stream>>>(Ehi, Elo, WIhi, WIlo,
                                               ws + OFF_BS0D, ws + OFF_X0, 256, 2048, 0);
  lstm_seq_k<<<128, 256, 0, stream>>>(PW0D, PW1AD, PW1BD,
                                      ws + OFF_X0, ws + OFF_B1D,
                                      H0hi, H0lo, H1hi, H1lo,
                                      H0hi + (size_t)127 * SLOT, H0lo + (size_t)127 * SLOT,
                                      H1hi + (size_t)127 * SLOT, H1lo + (size_t)127 * SLOT,
                                      ws + OFF_C0, ws + OFF_C1,
                                      ws + OFF_C0, ws + OFF_C1,
                                      dflag);

  // ---- vocab projection: A = dec h1 slots (bf16 hi/lo, amode=1 row remap) ----
  split_k<<<16000, 256, 0, stream>>>(Wout, Bhi, Blo);
  gemm_bfs_k<<<dim3(32, 250), 256, 0, stream>>>(H1hi, H1lo, Bhi, Blo,
                                                bout, (float*)d_out, 512, 32000, 1);
}